// Round 2
// baseline (2106.842 us; speedup 1.0000x reference)
//
#include <hip/hip_runtime.h>

typedef unsigned short u16;
typedef unsigned int u32;

constexpr int B = 2, L = 16, C = 64, S = 64, W = 128, R = 32, MH = 32;
constexpr int BL = B * L;        // 32
constexpr int SW = S * W;        // 8192
constexpr int CR = C * R;        // 2048
constexpr int F2 = C * R * 2;    // 4096

__device__ __forceinline__ float us2f(u16 h) { return __uint_as_float(((u32)h) << 16); }
__device__ __forceinline__ float bf_lo(u32 u) { return __uint_as_float(u << 16); }
__device__ __forceinline__ float bf_hi(u32 u) { return __uint_as_float(u & 0xffff0000u); }
__device__ __forceinline__ u16 f2bu(float f) {
  u32 u = __float_as_uint(f);
  u32 r = (u + 0x7fffu + ((u >> 16) & 1u)) >> 16;
  return (u16)r;
}
__device__ __forceinline__ u32 pack2(float lo, float hi) {
  return (u32)f2bu(lo) | ((u32)f2bu(hi) << 16);
}

// ---------------- prep: lam, gamma ----------------
__global__ void k_prep(const float* __restrict__ nu_log, const float* __restrict__ th_log,
                       const float* __restrict__ dnu, const float* __restrict__ dth,
                       float* __restrict__ lamr, float* __restrict__ lami,
                       float* __restrict__ gam) {
  int i = blockIdx.x * 256 + threadIdx.x;
  if (i >= CR) return;
  float nu = expf(nu_log[i] + dnu[i]);
  float th = expf(th_log[i] + dth[i]);
  float mag = expf(-nu);
  lamr[i] = mag * cosf(th);
  lami[i] = mag * sinf(th);
  gam[i] = sqrtf(fmaxf(1.0f - mag * mag, 1e-6f));
}

// ---------------- prep: effective conv kernel (fuse folded into 3x3) ----------------
__global__ void k_keff(const float* __restrict__ fuse_k, const float* __restrict__ fuse_b,
                       const float* __restrict__ convr_k, const float* __restrict__ convr_b,
                       const float* __restrict__ convi_k, const float* __restrict__ convi_b,
                       float* __restrict__ keff, float* __restrict__ biaseff) {
  int i = blockIdx.x * 256 + threadIdx.x;
  if (i < C * 2 * C * 9) {           // layout: ((o*128)+cin2)*9 + k
    int o = i / (2 * C * 9);
    int rem = i - o * (2 * C * 9);
    int cin2 = rem / 9;
    int k = rem - cin2 * 9;
    const float* ck = (cin2 < C) ? convr_k : convi_k;
    int cin = cin2 & (C - 1);
    int fbase = o * 2 * C + ((cin2 < C) ? 0 : C);
    float acc = 0.f;
    for (int m = 0; m < C; ++m)
      acc += fuse_k[fbase + m] * ck[(m * C + cin) * 9 + k];
    keff[i] = acc;
  } else if (i < C * 2 * C * 9 + C) {
    int o = i - C * 2 * C * 9;
    float acc = fuse_b[o];
    for (int m = 0; m < C; ++m) {
      acc += fuse_k[o * 2 * C + m] * convr_b[m];
      acc += fuse_k[o * 2 * C + C + m] * convi_b[m];
    }
    biaseff[o] = acc;
  }
}

// ---------------- ctx pooling ----------------
__global__ __launch_bounds__(256) void k_ctx(const float* __restrict__ x, float* __restrict__ ctx) {
  int blc = blockIdx.x;
  const float4* xp = (const float4*)(x + (size_t)blc * SW);
  float sm = 0.f;
  for (int i = threadIdx.x; i < SW / 4; i += 256) {
    float4 v = xp[i];
    sm += v.x + v.y + v.z + v.w;
  }
  __shared__ float red[256];
  red[threadIdx.x] = sm;
  __syncthreads();
  for (int off = 128; off > 0; off >>= 1) {
    if (threadIdx.x < off) red[threadIdx.x] += red[threadIdx.x + off];
    __syncthreads();
  }
  if (threadIdx.x == 0) ctx[blc] = red[0] * (1.f / SW);
}

// ---------------- MLP -> forcing ----------------
__global__ __launch_bounds__(256) void k_mlp(
    const float* __restrict__ ctx, const float* __restrict__ w1, const float* __restrict__ b1,
    const float* __restrict__ w2, const float* __restrict__ b2, const float* __restrict__ fscale,
    float* __restrict__ forcing) {
  int bl = blockIdx.x;
  __shared__ float cv[C];
  __shared__ float hid[MH];
  int t = threadIdx.x;
  if (t < C) cv[t] = ctx[bl * C + t];
  __syncthreads();
  if (t < MH) {
    float a = b1[t];
    for (int c2 = 0; c2 < C; ++c2) a += cv[c2] * w1[c2 * MH + t];
    hid[t] = tanhf(a);
  }
  __syncthreads();
  float scale = fscale[0];
  for (int k = t; k < F2; k += 256) {
    float a = b2[k];
    for (int j = 0; j < MH; ++j) a += hid[j] * w2[j * F2 + k];
    forcing[bl * F2 + k] = scale * a;
  }
}

// ---------------- encode: u[b,l,c,r] = gamma*(1+forcing)*sum_{s,w} x conj(U) conj(V) ----------------
__global__ __launch_bounds__(256) void k_u(
    const float* __restrict__ x,
    const float* __restrict__ Vr, const float* __restrict__ Vi,
    const float* __restrict__ Ur, const float* __restrict__ Ui,
    const float* __restrict__ gam, const float* __restrict__ forcing,
    float* __restrict__ u) {
  int blc = blockIdx.x;
  int c = blc & (C - 1);
  __shared__ u32 xs_u[SW / 2];       // x field as bf16 pairs, 16 KB
  __shared__ u16 vtr[2][R][W + 2];   // V transposed [r][w], padded, 16.25 KB
  __shared__ float y1[2][S * R];     // 16 KB
  int t = threadIdx.x;
  {
    const float4* xp = (const float4*)(x + (size_t)blc * SW);
    for (int i = t; i < SW / 4; i += 256) {
      float4 v = xp[i];
      xs_u[i * 2]     = pack2(v.x, v.y);
      xs_u[i * 2 + 1] = pack2(v.z, v.w);
    }
  }
  {
    const float* vrp = Vr + (size_t)c * (W * R);
    const float* vip = Vi + (size_t)c * (W * R);
    for (int i = t; i < W * R; i += 256) {
      int w = i >> 5, r = i & 31;
      vtr[0][r][w] = f2bu(vrp[i]);
      vtr[1][r][w] = f2bu(vip[i]);
    }
  }
  __syncthreads();
  // y1[s][r] = sum_w x[s,w] * conj(V[c,w,r])
  for (int p = t; p < S * R; p += 256) {
    int s = p >> 5, r = p & 31;
    const u32* xrow = xs_u + s * (W / 2);
    const u32* vrow_r = (const u32*)&vtr[0][r][0];
    const u32* vrow_i = (const u32*)&vtr[1][r][0];
    float ar = 0.f, ai = 0.f;
    for (int j = 0; j < W / 2; ++j) {
      u32 xv = xrow[j], vr = vrow_r[j], vi = vrow_i[j];
      float x0 = bf_lo(xv), x1 = bf_hi(xv);
      ar += x0 * bf_lo(vr) + x1 * bf_hi(vr);
      ai -= x0 * bf_lo(vi) + x1 * bf_hi(vi);
    }
    y1[0][p] = ar;
    y1[1][p] = ai;
  }
  __syncthreads();
  // u[r] = sum_s conj(U[c,s,r]) * y1[s,r], then gamma*(1+forcing)
  if (t < R) {
    int r = t;
    const float* urp = Ur + (size_t)c * (S * R);
    const float* uip = Ui + (size_t)c * (S * R);
    float sr = 0.f, si = 0.f;
    for (int s = 0; s < S; ++s) {
      float urv = urp[s * R + r];
      float uiv = uip[s * R + r];
      float yr = y1[0][s * R + r], yi = y1[1][s * R + r];
      sr += urv * yr + uiv * yi;
      si += urv * yi - uiv * yr;
    }
    float g = gam[c * R + r];
    float fr = forcing[(blc * R + r) * 2];
    float fi = forcing[(blc * R + r) * 2 + 1];
    float ofr = 1.f + fr;
    u[(blc * R + r) * 2]     = g * (sr * ofr - si * fi);
    u[(blc * R + r) * 2 + 1] = g * (sr * fi + si * ofr);
  }
}

// ---------------- diagonal scan over L ----------------
__global__ void k_scan(const float* __restrict__ lamr, const float* __restrict__ lami,
                       const float* __restrict__ u, float* __restrict__ h) {
  int i = blockIdx.x * 256 + threadIdx.x;   // b*CR + cr
  if (i >= B * CR) return;
  int b = i / CR;
  int cr = i - b * CR;
  float lr = lamr[cr], li = lami[cr];
  float hr = 0.f, hi = 0.f;
  for (int l = 0; l < L; ++l) {
    size_t off = ((size_t)(b * L + l) * CR + cr) * 2;
    float ur = u[off], ui = u[off + 1];
    float nr = lr * hr - li * hi + ur;
    float ni = lr * hi + li * hr + ui;
    hr = nr; hi = ni;
    h[off] = hr; h[off + 1] = hi;
  }
}

// ---------------- decode (h -> y) + channel projection, fused ----------------
__global__ __launch_bounds__(256) void k_recon(
    const float* __restrict__ h,
    const float* __restrict__ Ur, const float* __restrict__ Ui,
    const float* __restrict__ Vr, const float* __restrict__ Vi,
    const float* __restrict__ pWr, const float* __restrict__ pWi,
    const float* __restrict__ pbr, const float* __restrict__ pbi,
    u16* __restrict__ yr_out, u16* __restrict__ yi_out) {
  int bls = blockIdx.x;
  int s = bls & (S - 1);
  int bl = bls >> 6;
  __shared__ float smem0[4160];   // stage A/B: ar|ai (16 KB); stage C: pwri interleaved bf16
  __shared__ u16 ybr[C * W];
  __shared__ u16 ybi[C * W];
  float* ar_s = smem0;
  float* ai_s = smem0 + CR;
  u16* pwri = (u16*)smem0;
  int t = threadIdx.x;
  // a[c,r] = h[bl,c,r] * U[c,s,r]
  for (int p = t; p < CR; p += 256) {
    int c = p >> 5, r = p & 31;
    size_t hoff = ((size_t)(bl * C + c) * R + r) * 2;
    float hr = h[hoff], hi = h[hoff + 1];
    float urv = Ur[((size_t)c * S + s) * R + r];
    float uiv = Ui[((size_t)c * S + s) * R + r];
    ar_s[p] = hr * urv - hi * uiv;
    ai_s[p] = hr * uiv + hi * urv;
  }
  __syncthreads();
  // y[c,w] = sum_r a[c,r]*V[c,w,r]
  for (int p = t; p < C * W; p += 256) {
    int c = p >> 7, w = p & 127;
    const float4* vr4 = (const float4*)(Vr + ((size_t)c * W + w) * R);
    const float4* vi4 = (const float4*)(Vi + ((size_t)c * W + w) * R);
    const float* arp = ar_s + c * R;
    const float* aip = ai_s + c * R;
    float accr = 0.f, acci = 0.f;
#pragma unroll
    for (int q = 0; q < 8; ++q) {
      float4 va = vr4[q], vb = vi4[q];
      float vrv[4] = {va.x, va.y, va.z, va.w};
      float viv[4] = {vb.x, vb.y, vb.z, vb.w};
#pragma unroll
      for (int m = 0; m < 4; ++m) {
        int r = q * 4 + m;
        float a0r = arp[r], a0i = aip[r];
        accr += a0r * vrv[m] - a0i * viv[m];
        acci += a0r * viv[m] + a0i * vrv[m];
      }
    }
    ybr[p] = f2bu(accr);
    ybi[p] = f2bu(acci);
  }
  __syncthreads();
  // stage C prep: projW interleaved (pr,pi) bf16 per (cc,o), padded rows vs bank conflicts
  for (int idx = t; idx < C * C; idx += 256) {
    int o = idx >> 6, cc = idx & 63;
    pwri[cc * 130 + o * 2]     = f2bu(pWr[idx]);
    pwri[cc * 130 + o * 2 + 1] = f2bu(pWi[idx]);
  }
  __syncthreads();
  // yp[o,w] = sum_c projW[o,c]*y[c,w] + projb[o]
  int w = t & 127, obase = t >> 7;
  float accr[32], acci[32];
#pragma unroll
  for (int i = 0; i < 32; ++i) { accr[i] = 0.f; acci[i] = 0.f; }
  for (int cc = 0; cc < C; ++cc) {
    float yrv = us2f(ybr[cc * W + w]);
    float yiv = us2f(ybi[cc * W + w]);
#pragma unroll
    for (int i = 0; i < 32; ++i) {
      int o = obase + 2 * i;
      u32 pv = *(const u32*)&pwri[cc * 130 + o * 2];
      float pr = bf_lo(pv), pi = bf_hi(pv);
      accr[i] += pr * yrv - pi * yiv;
      acci[i] += pr * yiv + pi * yrv;
    }
  }
#pragma unroll
  for (int i = 0; i < 32; ++i) {
    int o = obase + 2 * i;
    size_t off = ((size_t)(bl * C + o) * S + s) * W + w;
    yr_out[off] = f2bu(accr[i] + pbr[o]);
    yi_out[off] = f2bu(acci[i] + pbi[o]);
  }
}

// ---------------- zero stats ----------------
__global__ void k_zero(float* __restrict__ p, int n) {
  int i = blockIdx.x * 256 + threadIdx.x;
  if (i < n) p[i] = 0.f;
}

// ---------------- fused 3x3 conv (128 in-ch -> 64 out) + LN partial stats ----------------
__global__ __launch_bounds__(256) void k_conv(
    const u16* __restrict__ yr, const u16* __restrict__ yi,
    const float* __restrict__ keff, const float* __restrict__ biaseff,
    u16* __restrict__ fused, float* __restrict__ stats) {
  int bid = blockIdx.x;
  int og = bid & 7;
  int st = (bid >> 3) & 7;
  int bl = bid >> 6;
  int s0 = st * 8;
  int o0 = og * 8;
  __shared__ float keff_s[8 * 128 * 9];   // 36 KB
  __shared__ float tile[10 * 132];        // 5.28 KB
  __shared__ float red[8 * 4 * 2];
  int t = threadIdx.x;
  for (int i = t; i < 8 * 128 * 9; i += 256)
    keff_s[i] = keff[o0 * 128 * 9 + i];
  float acc[4][8];
#pragma unroll
  for (int i = 0; i < 4; ++i)
#pragma unroll
    for (int o = 0; o < 8; ++o) acc[i][o] = 0.f;
  int col = t & 127;
  int r0 = t >> 7;
  for (int cin2 = 0; cin2 < 128; ++cin2) {
    const u16* sp = ((cin2 < C) ? yr : yi) + (size_t)(bl * C + (cin2 & 63)) * SW;
    __syncthreads();
    for (int i = t; i < 1300; i += 256) {
      int tr = i / 130;
      int tc = i - tr * 130;
      int ss = s0 - 1 + tr;
      int ww = tc - 1;
      float v = 0.f;
      if (ss >= 0 && ss < S && (unsigned)ww < (unsigned)W) v = us2f(sp[ss * W + ww]);
      tile[tr * 132 + tc] = v;
    }
    __syncthreads();
    float n[4][9];
#pragma unroll
    for (int i = 0; i < 4; ++i) {
      int row = r0 + 2 * i;
#pragma unroll
      for (int dr = 0; dr < 3; ++dr)
#pragma unroll
        for (int dc = 0; dc < 3; ++dc)
          n[i][dr * 3 + dc] = tile[(row + dr) * 132 + col + dc];
    }
#pragma unroll
    for (int ol = 0; ol < 8; ++ol) {
      const float* kp = keff_s + (ol * 128 + cin2) * 9;
      float k0 = kp[0], k1 = kp[1], k2 = kp[2], k3 = kp[3], k4 = kp[4],
            k5 = kp[5], k6 = kp[6], k7 = kp[7], k8 = kp[8];
#pragma unroll
      for (int i = 0; i < 4; ++i) {
        acc[i][ol] += k0 * n[i][0] + k1 * n[i][1] + k2 * n[i][2]
                    + k3 * n[i][3] + k4 * n[i][4] + k5 * n[i][5]
                    + k6 * n[i][6] + k7 * n[i][7] + k8 * n[i][8];
      }
    }
  }
  float bsum[8], bsq[8];
#pragma unroll
  for (int ol = 0; ol < 8; ++ol) { bsum[ol] = 0.f; bsq[ol] = 0.f; }
#pragma unroll
  for (int i = 0; i < 4; ++i) {
    int row = r0 + 2 * i;
    int ss = s0 + row;
#pragma unroll
    for (int ol = 0; ol < 8; ++ol) {
      float v = acc[i][ol] + biaseff[o0 + ol];
      fused[((size_t)(bl * C + o0 + ol) * S + ss) * W + col] = f2bu(v);
      bsum[ol] += v;
      bsq[ol] += v * v;
    }
  }
  int lane = t & 63, wid = t >> 6;
#pragma unroll
  for (int ol = 0; ol < 8; ++ol) {
    float sm = bsum[ol], qm = bsq[ol];
#pragma unroll
    for (int off = 32; off > 0; off >>= 1) {
      sm += __shfl_down(sm, off, 64);
      qm += __shfl_down(qm, off, 64);
    }
    if (lane == 0) { red[(ol * 4 + wid) * 2] = sm; red[(ol * 4 + wid) * 2 + 1] = qm; }
  }
  __syncthreads();
  if (t < 16) {
    int ol = t >> 1, q = t & 1;
    float v = red[(ol * 4 + 0) * 2 + q] + red[(ol * 4 + 1) * 2 + q]
            + red[(ol * 4 + 2) * 2 + q] + red[(ol * 4 + 3) * 2 + q];
    atomicAdd(&stats[(bl * C + o0 + ol) * 2 + q], v);
  }
}

// ---------------- layernorm + residual ----------------
__global__ __launch_bounds__(256) void k_ln(
    const u16* __restrict__ fused, const float* __restrict__ stats,
    const float* __restrict__ ln_g, const float* __restrict__ ln_b,
    const float* __restrict__ x, float* __restrict__ out) {
  int blc = blockIdx.x;
  const u16* fp = fused + (size_t)blc * SW;
  const float* xp = x + (size_t)blc * SW;
  float* op = out + (size_t)blc * SW;
  float mu = stats[blc * 2] * (1.f / SW);
  float var = stats[blc * 2 + 1] * (1.f / SW) - mu * mu;
  float rstd = rsqrtf(var + 1e-5f);
  for (int i = threadIdx.x; i < SW; i += 256) {
    float v = (us2f(fp[i]) - mu) * rstd * ln_g[i] + ln_b[i] + xp[i];
    op[i] = v;
  }
}

extern "C" void kernel_launch(void* const* d_in, const int* in_sizes, int n_in,
                              void* d_out, int out_size, void* d_ws, size_t ws_size,
                              hipStream_t stream) {
  (void)in_sizes; (void)n_in; (void)out_size; (void)ws_size;
  const float* x       = (const float*)d_in[0];
  const float* nu_log  = (const float*)d_in[1];
  const float* th_log  = (const float*)d_in[2];
  const float* dnu     = (const float*)d_in[3];
  const float* dth     = (const float*)d_in[4];
  const float* w1      = (const float*)d_in[5];
  const float* b1      = (const float*)d_in[6];
  const float* w2      = (const float*)d_in[7];
  const float* b2      = (const float*)d_in[8];
  const float* fscale  = (const float*)d_in[9];
  const float* Ur      = (const float*)d_in[10];
  const float* Ui      = (const float*)d_in[11];
  const float* Vr      = (const float*)d_in[12];
  const float* Vi      = (const float*)d_in[13];
  const float* pWr     = (const float*)d_in[14];
  const float* pWi     = (const float*)d_in[15];
  const float* pbr     = (const float*)d_in[16];
  const float* pbi     = (const float*)d_in[17];
  const float* convr_k = (const float*)d_in[18];
  const float* convr_b = (const float*)d_in[19];
  const float* convi_k = (const float*)d_in[20];
  const float* convi_b = (const float*)d_in[21];
  const float* fuse_k  = (const float*)d_in[22];
  const float* fuse_b  = (const float*)d_in[23];
  const float* ln_g    = (const float*)d_in[24];
  const float* ln_b    = (const float*)d_in[25];
  float* out = (float*)d_out;

  char* ws = (char*)d_ws;
  float* lamr    = (float*)ws;
  float* lami    = lamr + 2048;
  float* gam     = lami + 2048;
  float* keff    = gam + 2048;        // 73728 floats
  float* biaseff = keff + 73728;      // 64
  float* ctx     = biaseff + 64;      // 2048
  float* forcing = ctx + 2048;        // 131072
  float* ubuf    = forcing + 131072;  // 131072
  float* hbuf    = ubuf + 131072;     // 131072
  float* stats   = hbuf + 131072;     // 4096
  u16* yrb       = (u16*)(stats + 4096);        // 16777216 bf16 (32 MB)
  u16* yib       = yrb + 16777216;              // 16777216 bf16 (32 MB)
  u16* fused     = yib + 16777216;              // 16777216 bf16 (32 MB)
  // total ws: ~98 MB

  k_prep<<<8, 256, 0, stream>>>(nu_log, th_log, dnu, dth, lamr, lami, gam);
  k_keff<<<289, 256, 0, stream>>>(fuse_k, fuse_b, convr_k, convr_b, convi_k, convi_b,
                                  keff, biaseff);
  k_ctx<<<BL * C, 256, 0, stream>>>(x, ctx);
  k_mlp<<<BL, 256, 0, stream>>>(ctx, w1, b1, w2, b2, fscale, forcing);
  k_u<<<BL * C, 256, 0, stream>>>(x, Vr, Vi, Ur, Ui, gam, forcing, ubuf);
  k_scan<<<16, 256, 0, stream>>>(lamr, lami, ubuf, hbuf);
  k_recon<<<BL * S, 256, 0, stream>>>(hbuf, Ur, Ui, Vr, Vi, pWr, pWi, pbr, pbi, yrb, yib);
  k_zero<<<16, 256, 0, stream>>>(stats, B * L * C * 2);
  k_conv<<<2048, 256, 0, stream>>>(yrb, yib, keff, biaseff, fused, stats);
  k_ln<<<BL * C, 256, 0, stream>>>(fused, stats, ln_g, ln_b, x, out);
}

// Round 3
// 819.761 us; speedup vs baseline: 2.5701x; 2.5701x over previous
//
#include <hip/hip_runtime.h>

typedef unsigned short u16;
typedef unsigned int u32;
typedef __attribute__((ext_vector_type(8))) short short8;
typedef __attribute__((ext_vector_type(4))) float f32x4;

constexpr int B = 2, L = 16, C = 64, S = 64, W = 128, R = 32, MH = 32;
constexpr int BL = B * L;        // 32
constexpr int SW = S * W;        // 8192
constexpr int CR = C * R;        // 2048
constexpr int F2 = C * R * 2;    // 4096

__device__ __forceinline__ float us2f(u16 h) { return __uint_as_float(((u32)h) << 16); }
__device__ __forceinline__ float bf_lo(u32 u) { return __uint_as_float(u << 16); }
__device__ __forceinline__ float bf_hi(u32 u) { return __uint_as_float(u & 0xffff0000u); }
__device__ __forceinline__ u16 f2bu(float f) {
  u32 u = __float_as_uint(f);
  u32 r = (u + 0x7fffu + ((u >> 16) & 1u)) >> 16;
  return (u16)r;
}
__device__ __forceinline__ u32 pack2(float lo, float hi) {
  return (u32)f2bu(lo) | ((u32)f2bu(hi) << 16);
}

// ---------------- prep: lam, gamma ----------------
__global__ void k_prep(const float* __restrict__ nu_log, const float* __restrict__ th_log,
                       const float* __restrict__ dnu, const float* __restrict__ dth,
                       float* __restrict__ lamr, float* __restrict__ lami,
                       float* __restrict__ gam) {
  int i = blockIdx.x * 256 + threadIdx.x;
  if (i >= CR) return;
  float nu = expf(nu_log[i] + dnu[i]);
  float th = expf(th_log[i] + dth[i]);
  float mag = expf(-nu);
  lamr[i] = mag * cosf(th);
  lami[i] = mag * sinf(th);
  gam[i] = sqrtf(fmaxf(1.0f - mag * mag, 1e-6f));
}

// ---------------- prep: effective conv kernel (fuse folded), MFMA-A-swizzled bf16 ----------------
// A[m=o][k], k = seg*128 + cin2 within seg; MFMA 16x16x32 A frag: m=lane&15, k=(lane>>4)*8+j
// layout: keff_bf[(((seg*4+kstep)*4 + m_tile)*64 + lane)*8 + j]
__global__ void k_keff(const float* __restrict__ fuse_k, const float* __restrict__ fuse_b,
                       const float* __restrict__ convr_k, const float* __restrict__ convr_b,
                       const float* __restrict__ convi_k, const float* __restrict__ convi_b,
                       u16* __restrict__ keff_bf, float* __restrict__ biaseff) {
  int i = blockIdx.x * 256 + threadIdx.x;
  if (i < C * 2 * C * 9) {
    int o = i / (2 * C * 9);
    int rem = i - o * (2 * C * 9);
    int cin2 = rem / 9;
    int seg = rem - cin2 * 9;          // seg = dr*3+dc = kernel tap index
    const float* ck = (cin2 < C) ? convr_k : convi_k;
    int cin = cin2 & (C - 1);
    int fbase = o * 2 * C + ((cin2 < C) ? 0 : C);
    float acc = 0.f;
    for (int m = 0; m < C; ++m)
      acc += fuse_k[fbase + m] * ck[(m * C + cin) * 9 + seg];
    int kstep = cin2 >> 5;
    int kk = cin2 & 31;
    int lane = (o & 15) | ((kk >> 3) << 4);
    int j = kk & 7;
    int m_tile = o >> 4;
    keff_bf[((((seg * 4 + kstep) * 4 + m_tile) * 64 + lane) << 3) + j] = f2bu(acc);
  } else if (i < C * 2 * C * 9 + C) {
    int o = i - C * 2 * C * 9;
    float acc = fuse_b[o];
    for (int m = 0; m < C; ++m) {
      acc += fuse_k[o * 2 * C + m] * convr_b[m];
      acc += fuse_k[o * 2 * C + C + m] * convi_b[m];
    }
    biaseff[o] = acc;
  }
}

// ---------------- pack V into interleaved bf16 ----------------
__global__ void k_vpack(const float* __restrict__ Vr, const float* __restrict__ Vi,
                        u32* __restrict__ vp) {
  int i = blockIdx.x * 256 + threadIdx.x;
  if (i < C * W * R) vp[i] = pack2(Vr[i], Vi[i]);
}

// ---------------- ctx pooling ----------------
__global__ __launch_bounds__(256) void k_ctx(const float* __restrict__ x, float* __restrict__ ctx) {
  int blc = blockIdx.x;
  const float4* xp = (const float4*)(x + (size_t)blc * SW);
  float sm = 0.f;
  for (int i = threadIdx.x; i < SW / 4; i += 256) {
    float4 v = xp[i];
    sm += v.x + v.y + v.z + v.w;
  }
  __shared__ float red[256];
  red[threadIdx.x] = sm;
  __syncthreads();
  for (int off = 128; off > 0; off >>= 1) {
    if (threadIdx.x < off) red[threadIdx.x] += red[threadIdx.x + off];
    __syncthreads();
  }
  if (threadIdx.x == 0) ctx[blc] = red[0] * (1.f / SW);
}

// ---------------- MLP -> forcing ----------------
__global__ __launch_bounds__(256) void k_mlp(
    const float* __restrict__ ctx, const float* __restrict__ w1, const float* __restrict__ b1,
    const float* __restrict__ w2, const float* __restrict__ b2, const float* __restrict__ fscale,
    float* __restrict__ forcing) {
  int bl = blockIdx.x;
  __shared__ float cv[C];
  __shared__ float hid[MH];
  int t = threadIdx.x;
  if (t < C) cv[t] = ctx[bl * C + t];
  __syncthreads();
  if (t < MH) {
    float a = b1[t];
    for (int c2 = 0; c2 < C; ++c2) a += cv[c2] * w1[c2 * MH + t];
    hid[t] = tanhf(a);
  }
  __syncthreads();
  float scale = fscale[0];
  for (int k = t; k < F2; k += 256) {
    float a = b2[k];
    for (int j = 0; j < MH; ++j) a += hid[j] * w2[j * F2 + k];
    forcing[bl * F2 + k] = scale * a;
  }
}

// ---------------- encode ----------------
__global__ __launch_bounds__(256) void k_u(
    const float* __restrict__ x,
    const float* __restrict__ Vr, const float* __restrict__ Vi,
    const float* __restrict__ Ur, const float* __restrict__ Ui,
    const float* __restrict__ gam, const float* __restrict__ forcing,
    float* __restrict__ u) {
  int blc = blockIdx.x;
  int c = blc & (C - 1);
  __shared__ u32 xs_u[SW / 2];
  __shared__ u16 vtr[2][R][W + 2];
  __shared__ float y1[2][S * R];
  int t = threadIdx.x;
  {
    const float4* xp = (const float4*)(x + (size_t)blc * SW);
    for (int i = t; i < SW / 4; i += 256) {
      float4 v = xp[i];
      xs_u[i * 2]     = pack2(v.x, v.y);
      xs_u[i * 2 + 1] = pack2(v.z, v.w);
    }
  }
  {
    const float* vrp = Vr + (size_t)c * (W * R);
    const float* vip = Vi + (size_t)c * (W * R);
    for (int i = t; i < W * R; i += 256) {
      int w = i >> 5, r = i & 31;
      vtr[0][r][w] = f2bu(vrp[i]);
      vtr[1][r][w] = f2bu(vip[i]);
    }
  }
  __syncthreads();
  for (int p = t; p < S * R; p += 256) {
    int s = p >> 5, r = p & 31;
    const u32* xrow = xs_u + s * (W / 2);
    const u32* vrow_r = (const u32*)&vtr[0][r][0];
    const u32* vrow_i = (const u32*)&vtr[1][r][0];
    float ar = 0.f, ai = 0.f;
    for (int j = 0; j < W / 2; ++j) {
      u32 xv = xrow[j], vr = vrow_r[j], vi = vrow_i[j];
      float x0 = bf_lo(xv), x1 = bf_hi(xv);
      ar += x0 * bf_lo(vr) + x1 * bf_hi(vr);
      ai -= x0 * bf_lo(vi) + x1 * bf_hi(vi);
    }
    y1[0][p] = ar;
    y1[1][p] = ai;
  }
  __syncthreads();
  if (t < R) {
    int r = t;
    const float* urp = Ur + (size_t)c * (S * R);
    const float* uip = Ui + (size_t)c * (S * R);
    float sr = 0.f, si = 0.f;
    for (int s = 0; s < S; ++s) {
      float urv = urp[s * R + r];
      float uiv = uip[s * R + r];
      float yr = y1[0][s * R + r], yi = y1[1][s * R + r];
      sr += urv * yr + uiv * yi;
      si += urv * yi - uiv * yr;
    }
    float g = gam[c * R + r];
    float fr = forcing[(blc * R + r) * 2];
    float fi = forcing[(blc * R + r) * 2 + 1];
    float ofr = 1.f + fr;
    u[(blc * R + r) * 2]     = g * (sr * ofr - si * fi);
    u[(blc * R + r) * 2 + 1] = g * (sr * fi + si * ofr);
  }
}

// ---------------- diagonal scan over L ----------------
__global__ void k_scan(const float* __restrict__ lamr, const float* __restrict__ lami,
                       const float* __restrict__ u, float* __restrict__ h) {
  int i = blockIdx.x * 256 + threadIdx.x;
  if (i >= B * CR) return;
  int b = i / CR;
  int cr = i - b * CR;
  float lr = lamr[cr], li = lami[cr];
  float hr = 0.f, hi = 0.f;
  for (int l = 0; l < L; ++l) {
    size_t off = ((size_t)(b * L + l) * CR + cr) * 2;
    float ur = u[off], ui = u[off + 1];
    float nr = lr * hr - li * hi + ur;
    float ni = lr * hi + li * hr + ui;
    hr = nr; hi = ni;
    h[off] = hr; h[off + 1] = hi;
  }
}

// ---------------- decode + channel projection -> NHWC bf16 ----------------
__global__ __launch_bounds__(256) void k_recon(
    const float* __restrict__ h,
    const float* __restrict__ Ur, const float* __restrict__ Ui,
    const u32* __restrict__ vpack,
    const float* __restrict__ pWr, const float* __restrict__ pWi,
    const float* __restrict__ pbr, const float* __restrict__ pbi,
    u16* __restrict__ ynhwc) {
  int bls = blockIdx.x;
  int s = bls & (S - 1);
  int bl = bls >> 6;
  __shared__ float smem0[4160];     // stages A/B: ar|ai; stage C: pw32 (4096 u32)
  __shared__ u16 ybr[C * W];
  __shared__ u16 ybi[C * W];
  float* ar_s = smem0;
  float* ai_s = smem0 + CR;
  u32* pw32 = (u32*)smem0;
  int t = threadIdx.x;
  // a[c,r] = h[bl,c,r] * U[c,s,r]
  for (int p = t; p < CR; p += 256) {
    int c = p >> 5, r = p & 31;
    size_t hoff = ((size_t)(bl * C + c) * R + r) * 2;
    float hr = h[hoff], hi = h[hoff + 1];
    float urv = Ur[((size_t)c * S + s) * R + r];
    float uiv = Ui[((size_t)c * S + s) * R + r];
    ar_s[p] = hr * urv - hi * uiv;
    ai_s[p] = hr * uiv + hi * urv;
  }
  __syncthreads();
  // y[c,w] = sum_r a[c,r]*V[c,w,r]  (V packed bf16 interleaved)
  for (int p = t; p < C * W; p += 256) {
    int c = p >> 7, w = p & 127;
    const uint4* vp = (const uint4*)(vpack + ((size_t)c * W + w) * R);
    const float* arp = ar_s + c * R;
    const float* aip = ai_s + c * R;
    float accr = 0.f, acci = 0.f;
#pragma unroll
    for (int q = 0; q < 8; ++q) {
      uint4 v = vp[q];
      u32 e0 = v.x, e1 = v.y, e2 = v.z, e3 = v.w;
      int r = q * 4;
      float a0r = arp[r], a0i = aip[r];
      accr += a0r * bf_lo(e0) - a0i * bf_hi(e0);
      acci += a0r * bf_hi(e0) + a0i * bf_lo(e0);
      a0r = arp[r + 1]; a0i = aip[r + 1];
      accr += a0r * bf_lo(e1) - a0i * bf_hi(e1);
      acci += a0r * bf_hi(e1) + a0i * bf_lo(e1);
      a0r = arp[r + 2]; a0i = aip[r + 2];
      accr += a0r * bf_lo(e2) - a0i * bf_hi(e2);
      acci += a0r * bf_hi(e2) + a0i * bf_lo(e2);
      a0r = arp[r + 3]; a0i = aip[r + 3];
      accr += a0r * bf_lo(e3) - a0i * bf_hi(e3);
      acci += a0r * bf_hi(e3) + a0i * bf_lo(e3);
    }
    ybr[p] = f2bu(accr);
    ybi[p] = f2bu(acci);
  }
  __syncthreads();
  // stage C prep: projW interleaved bf16 pairs, layout pw32[cc*64 + o]
  for (int idx = t; idx < C * C; idx += 256) {
    int o = idx >> 6, cc = idx & 63;
    pw32[cc * 64 + o] = pack2(pWr[idx], pWi[idx]);
  }
  __syncthreads();
  // yp[o,w] = sum_c projW[o,c]*y[c,w] + projb[o]; write NHWC (r at ch=o, i at ch=64+o)
  int w = t & 127, half = t >> 7, ob = half * 32;
  float accr[32], acci[32];
#pragma unroll
  for (int i = 0; i < 32; ++i) { accr[i] = 0.f; acci[i] = 0.f; }
  for (int cc = 0; cc < C; ++cc) {
    float yrv = us2f(ybr[cc * W + w]);
    float yiv = us2f(ybi[cc * W + w]);
    const uint4* pw4 = (const uint4*)&pw32[cc * 64 + ob];
#pragma unroll
    for (int q = 0; q < 8; ++q) {
      uint4 pv4 = pw4[q];
      u32 e[4] = {pv4.x, pv4.y, pv4.z, pv4.w};
#pragma unroll
      for (int m = 0; m < 4; ++m) {
        int i = q * 4 + m;
        float pr = bf_lo(e[m]), pi = bf_hi(e[m]);
        accr[i] += pr * yrv - pi * yiv;
        acci[i] += pr * yiv + pi * yrv;
      }
    }
  }
  size_t base = (((size_t)bl * S + s) * W + w) * 128;
  u32 outw[16];
#pragma unroll
  for (int i = 0; i < 16; ++i)
    outw[i] = pack2(accr[2 * i] + pbr[ob + 2 * i], accr[2 * i + 1] + pbr[ob + 2 * i + 1]);
  {
    uint4* dst = (uint4*)(ynhwc + base + ob);
    const uint4* srcv = (const uint4*)outw;
#pragma unroll
    for (int q = 0; q < 4; ++q) dst[q] = srcv[q];
  }
#pragma unroll
  for (int i = 0; i < 16; ++i)
    outw[i] = pack2(acci[2 * i] + pbi[ob + 2 * i], acci[2 * i + 1] + pbi[ob + 2 * i + 1]);
  {
    uint4* dst = (uint4*)(ynhwc + base + 64 + ob);
    const uint4* srcv = (const uint4*)outw;
#pragma unroll
    for (int q = 0; q < 4; ++q) dst[q] = srcv[q];
  }
}

// ---------------- MFMA implicit-GEMM conv: M=64 outs, K=9 taps x 128 ch, N=2 rows x 32 w ----------------
__global__ __launch_bounds__(256) void k_conv(
    const u16* __restrict__ ynhwc, const u16* __restrict__ keff_bf,
    const float* __restrict__ biaseff, u16* __restrict__ fused) {
  int bid = blockIdx.x;
  int wt = bid & 3;
  int st = (bid >> 2) & 31;
  int bl = bid >> 7;
  int s0 = st * 2;
  int w0 = wt * 32;
  // window rows s0-1..s0+2, cols w0-1..w0+32 (34), 128 ch + 8 pad (272B col stride)
  __shared__ __align__(16) u16 win[4][34][136];
  int t = threadIdx.x;
  int c_lo = (w0 == 0) ? 1 : 0;
  int c_hi = (w0 == 96) ? 33 : 34;
  uint4 z4 = make_uint4(0u, 0u, 0u, 0u);
  for (int rr = 0; rr < 4; ++rr) {
    int rs = s0 - 1 + rr;
    if (rs < 0 || rs >= S) {
      uint4* wrow = (uint4*)&win[rr][0][0];
      for (int i = t; i < 578; i += 256) wrow[i] = z4;     // 34*136*2/16
    } else {
      if (w0 == 0 && t < 16) ((uint4*)&win[rr][0][0])[t] = z4;
      if (w0 == 96 && t < 16) ((uint4*)&win[rr][33][0])[t] = z4;
      const uint4* src = (const uint4*)(ynhwc + (((size_t)bl * S + rs) * W + (w0 - 1 + c_lo)) * 128);
      int n4 = (c_hi - c_lo) * 16;
      for (int i = t; i < n4; i += 256) {
        int col = i >> 4, q = i & 15;
        ((uint4*)&win[rr][c_lo + col][0])[q] = src[i];
      }
    }
  }
  __syncthreads();

  int lane = t & 63;
  int wv = t >> 6;
  int mp = wv & 1;        // m-tile pair: {2mp, 2mp+1}
  int np = wv >> 1;       // n-pair -> output row s0+np, w tiles {0,1}
  int quad = lane >> 4, l15 = lane & 15;
  int chq = quad * 8;     // k-chunk channel offset within 32-ch kstep

  f32x4 zf = {0.f, 0.f, 0.f, 0.f};
  f32x4 acc00 = zf, acc01 = zf, acc10 = zf, acc11 = zf;
  const short8* ap = (const short8*)keff_bf;

  for (int seg = 0; seg < 9; ++seg) {
    int dr = seg / 3;
    int dc = seg - dr * 3;
    const u16* b0base = &win[np + dr][l15 + dc][chq];
    const u16* b1base = b0base + 16 * 136;
#pragma unroll
    for (int ks = 0; ks < 4; ++ks) {
      short8 a0 = ap[((seg * 4 + ks) * 4 + 2 * mp) * 64 + lane];
      short8 a1 = ap[((seg * 4 + ks) * 4 + 2 * mp + 1) * 64 + lane];
      short8 b0 = *(const short8*)(b0base + ks * 32);
      short8 b1 = *(const short8*)(b1base + ks * 32);
      acc00 = __builtin_amdgcn_mfma_f32_16x16x32_bf16(a0, b0, acc00, 0, 0, 0);
      acc01 = __builtin_amdgcn_mfma_f32_16x16x32_bf16(a0, b1, acc01, 0, 0, 0);
      acc10 = __builtin_amdgcn_mfma_f32_16x16x32_bf16(a1, b0, acc10, 0, 0, 0);
      acc11 = __builtin_amdgcn_mfma_f32_16x16x32_bf16(a1, b1, acc11, 0, 0, 0);
    }
  }

  // C/D: row(m) = quad*4 + reg, col(n) = l15
  int s_out = s0 + np;
#pragma unroll
  for (int mi = 0; mi < 2; ++mi) {
    f32x4 aN0 = mi ? acc10 : acc00;
    f32x4 aN1 = mi ? acc11 : acc01;
#pragma unroll
    for (int reg = 0; reg < 4; ++reg) {
      int o = (2 * mp + mi) * 16 + quad * 4 + reg;
      float bias = biaseff[o];
      size_t rowoff = ((size_t)(bl * C + o) * S + s_out) * W;
      fused[rowoff + w0 + l15]      = f2bu(aN0[reg] + bias);
      fused[rowoff + w0 + 16 + l15] = f2bu(aN1[reg] + bias);
    }
  }
}

// ---------------- layernorm (stats in-kernel) + residual ----------------
__global__ __launch_bounds__(256) void k_ln(
    const u16* __restrict__ fused,
    const float* __restrict__ ln_g, const float* __restrict__ ln_b,
    const float* __restrict__ x, float* __restrict__ out) {
  int blc = blockIdx.x;
  __shared__ u16 fs[SW];
  __shared__ float red[12];
  int t = threadIdx.x;
  const uint4* fp = (const uint4*)(fused + (size_t)blc * SW);
  float sm = 0.f, sq = 0.f;
  for (int i = t; i < SW / 8; i += 256) {
    uint4 v = fp[i];
    ((uint4*)fs)[i] = v;
    float f0 = bf_lo(v.x), f1 = bf_hi(v.x), f2 = bf_lo(v.y), f3 = bf_hi(v.y);
    float f4 = bf_lo(v.z), f5 = bf_hi(v.z), f6 = bf_lo(v.w), f7 = bf_hi(v.w);
    sm += f0 + f1 + f2 + f3 + f4 + f5 + f6 + f7;
    sq += f0 * f0 + f1 * f1 + f2 * f2 + f3 * f3 + f4 * f4 + f5 * f5 + f6 * f6 + f7 * f7;
  }
#pragma unroll
  for (int off = 32; off > 0; off >>= 1) {
    sm += __shfl_down(sm, off, 64);
    sq += __shfl_down(sq, off, 64);
  }
  int lane = t & 63, wid = t >> 6;
  if (lane == 0) { red[wid * 2] = sm; red[wid * 2 + 1] = sq; }
  __syncthreads();
  if (t == 0) {
    float S1 = red[0] + red[2] + red[4] + red[6];
    float S2 = red[1] + red[3] + red[5] + red[7];
    float mu = S1 * (1.f / SW);
    float var = S2 * (1.f / SW) - mu * mu;
    red[8] = mu;
    red[9] = rsqrtf(var + 1e-5f);
  }
  __syncthreads();
  float mu = red[8], rstd = red[9];
  const float* xp = x + (size_t)blc * SW;
  float* op = out + (size_t)blc * SW;
  for (int i = t; i < SW; i += 256)
    op[i] = (us2f(fs[i]) - mu) * rstd * ln_g[i] + ln_b[i] + xp[i];
}

extern "C" void kernel_launch(void* const* d_in, const int* in_sizes, int n_in,
                              void* d_out, int out_size, void* d_ws, size_t ws_size,
                              hipStream_t stream) {
  (void)in_sizes; (void)n_in; (void)out_size; (void)ws_size;
  const float* x       = (const float*)d_in[0];
  const float* nu_log  = (const float*)d_in[1];
  const float* th_log  = (const float*)d_in[2];
  const float* dnu     = (const float*)d_in[3];
  const float* dth     = (const float*)d_in[4];
  const float* w1      = (const float*)d_in[5];
  const float* b1      = (const float*)d_in[6];
  const float* w2      = (const float*)d_in[7];
  const float* b2      = (const float*)d_in[8];
  const float* fscale  = (const float*)d_in[9];
  const float* Ur      = (const float*)d_in[10];
  const float* Ui      = (const float*)d_in[11];
  const float* Vr      = (const float*)d_in[12];
  const float* Vi      = (const float*)d_in[13];
  const float* pWr     = (const float*)d_in[14];
  const float* pWi     = (const float*)d_in[15];
  const float* pbr     = (const float*)d_in[16];
  const float* pbi     = (const float*)d_in[17];
  const float* convr_k = (const float*)d_in[18];
  const float* convr_b = (const float*)d_in[19];
  const float* convi_k = (const float*)d_in[20];
  const float* convi_b = (const float*)d_in[21];
  const float* fuse_k  = (const float*)d_in[22];
  const float* fuse_b  = (const float*)d_in[23];
  const float* ln_g    = (const float*)d_in[24];
  const float* ln_b    = (const float*)d_in[25];
  float* out = (float*)d_out;

  char* ws = (char*)d_ws;
  float* lamr    = (float*)ws;
  float* lami    = lamr + 2048;
  float* gam     = lami + 2048;
  float* biaseff = gam + 2048;        // 64
  float* ctx     = biaseff + 64;      // 2048
  float* forcing = ctx + 2048;        // 131072
  float* ubuf    = forcing + 131072;  // 131072
  float* hbuf    = ubuf + 131072;     // 131072
  u32* vpack     = (u32*)(hbuf + 131072);       // 262144 u32 (1 MB)
  u16* keff_bf   = (u16*)(vpack + 262144);      // 73728 u16 (144 KB)
  u16* ynhwc     = keff_bf + 73728;             // 33554432 u16 (64 MB)
  u16* fused     = ynhwc + 33554432;            // 16777216 u16 (32 MB)
  // total ws ~ 103.5 MB

  k_prep<<<8, 256, 0, stream>>>(nu_log, th_log, dnu, dth, lamr, lami, gam);
  k_keff<<<289, 256, 0, stream>>>(fuse_k, fuse_b, convr_k, convr_b, convi_k, convi_b,
                                  keff_bf, biaseff);
  k_vpack<<<1024, 256, 0, stream>>>(Vr, Vi, vpack);
  k_ctx<<<BL * C, 256, 0, stream>>>(x, ctx);
  k_mlp<<<BL, 256, 0, stream>>>(ctx, w1, b1, w2, b2, fscale, forcing);
  k_u<<<BL * C, 256, 0, stream>>>(x, Vr, Vi, Ur, Ui, gam, forcing, ubuf);
  k_scan<<<16, 256, 0, stream>>>(lamr, lami, ubuf, hbuf);
  k_recon<<<BL * S, 256, 0, stream>>>(hbuf, Ur, Ui, vpack, pWr, pWi, pbr, pbi, ynhwc);
  k_conv<<<4096, 256, 0, stream>>>(ynhwc, keff_bf, biaseff, fused);
  k_ln<<<BL * C, 256, 0, stream>>>(fused, ln_g, ln_b, x, out);
}

// Round 4
// 524.828 us; speedup vs baseline: 4.0143x; 1.5620x over previous
//
#include <hip/hip_runtime.h>

typedef unsigned short u16;
typedef unsigned int u32;
typedef __attribute__((ext_vector_type(8))) short short8;
typedef __attribute__((ext_vector_type(4))) float f32x4;

constexpr int B = 2, L = 16, C = 64, S = 64, W = 128, R = 32, MH = 32;
constexpr int BL = B * L;        // 32
constexpr int SW = S * W;        // 8192
constexpr int CR = C * R;        // 2048
constexpr int F2 = C * R * 2;    // 4096

__device__ __forceinline__ float us2f(u16 h) { return __uint_as_float(((u32)h) << 16); }
__device__ __forceinline__ float bf_lo(u32 u) { return __uint_as_float(u << 16); }
__device__ __forceinline__ float bf_hi(u32 u) { return __uint_as_float(u & 0xffff0000u); }
__device__ __forceinline__ u16 f2bu(float f) {
  u32 u = __float_as_uint(f);
  u32 r = (u + 0x7fffu + ((u >> 16) & 1u)) >> 16;
  return (u16)r;
}
__device__ __forceinline__ u32 pack2(float lo, float hi) {
  return (u32)f2bu(lo) | ((u32)f2bu(hi) << 16);
}

// ---------------- prep: lam, gamma ----------------
__global__ void k_prep(const float* __restrict__ nu_log, const float* __restrict__ th_log,
                       const float* __restrict__ dnu, const float* __restrict__ dth,
                       float* __restrict__ lamr, float* __restrict__ lami,
                       float* __restrict__ gam) {
  int i = blockIdx.x * 256 + threadIdx.x;
  if (i >= CR) return;
  float nu = expf(nu_log[i] + dnu[i]);
  float th = expf(th_log[i] + dth[i]);
  float mag = expf(-nu);
  lamr[i] = mag * cosf(th);
  lami[i] = mag * sinf(th);
  gam[i] = sqrtf(fmaxf(1.0f - mag * mag, 1e-6f));
}

// ---------------- prep: effective conv kernel (fuse folded), MFMA-A-swizzled bf16 ----------------
__global__ void k_keff(const float* __restrict__ fuse_k, const float* __restrict__ fuse_b,
                       const float* __restrict__ convr_k, const float* __restrict__ convr_b,
                       const float* __restrict__ convi_k, const float* __restrict__ convi_b,
                       u16* __restrict__ keff_bf, float* __restrict__ biaseff) {
  int i = blockIdx.x * 256 + threadIdx.x;
  if (i < C * 2 * C * 9) {
    int o = i / (2 * C * 9);
    int rem = i - o * (2 * C * 9);
    int cin2 = rem / 9;
    int seg = rem - cin2 * 9;
    const float* ck = (cin2 < C) ? convr_k : convi_k;
    int cin = cin2 & (C - 1);
    int fbase = o * 2 * C + ((cin2 < C) ? 0 : C);
    float acc = 0.f;
    for (int m = 0; m < C; ++m)
      acc += fuse_k[fbase + m] * ck[(m * C + cin) * 9 + seg];
    int kstep = cin2 >> 5;
    int kk = cin2 & 31;
    int lane = (o & 15) | ((kk >> 3) << 4);
    int j = kk & 7;
    int m_tile = o >> 4;
    keff_bf[((((seg * 4 + kstep) * 4 + m_tile) * 64 + lane) << 3) + j] = f2bu(acc);
  } else if (i < C * 2 * C * 9 + C) {
    int o = i - C * 2 * C * 9;
    float acc = fuse_b[o];
    for (int m = 0; m < C; ++m) {
      acc += fuse_k[o * 2 * C + m] * convr_b[m];
      acc += fuse_k[o * 2 * C + C + m] * convi_b[m];
    }
    biaseff[o] = acc;
  }
}

// ---------------- prep: projection matrix real-stacked bf16 [m=128][k=128] ----------------
// k = 2c (mult Yr), 2c+1 (mult Yi). m<64: real out rows; m>=64: imag out rows.
__global__ void k_apack(const float* __restrict__ pWr, const float* __restrict__ pWi,
                        u16* __restrict__ aproj) {
  int i = blockIdx.x * 256 + threadIdx.x;
  if (i >= 128 * 128) return;
  int m = i >> 7, k = i & 127;
  int c = k >> 1, im = k & 1;
  int o = m & 63;
  float v;
  if (m < 64) v = im ? -pWi[o * 64 + c] : pWr[o * 64 + c];
  else        v = im ?  pWr[o * 64 + c] : pWi[o * 64 + c];
  aproj[i] = f2bu(v);
}

// ---------------- ctx pooling ----------------
__global__ __launch_bounds__(256) void k_ctx(const float* __restrict__ x, float* __restrict__ ctx) {
  int blc = blockIdx.x;
  const float4* xp = (const float4*)(x + (size_t)blc * SW);
  float sm = 0.f;
  for (int i = threadIdx.x; i < SW / 4; i += 256) {
    float4 v = xp[i];
    sm += v.x + v.y + v.z + v.w;
  }
  __shared__ float red[256];
  red[threadIdx.x] = sm;
  __syncthreads();
  for (int off = 128; off > 0; off >>= 1) {
    if (threadIdx.x < off) red[threadIdx.x] += red[threadIdx.x + off];
    __syncthreads();
  }
  if (threadIdx.x == 0) ctx[blc] = red[0] * (1.f / SW);
}

// ---------------- MLP -> forcing ----------------
__global__ __launch_bounds__(256) void k_mlp(
    const float* __restrict__ ctx, const float* __restrict__ w1, const float* __restrict__ b1,
    const float* __restrict__ w2, const float* __restrict__ b2, const float* __restrict__ fscale,
    float* __restrict__ forcing) {
  int bl = blockIdx.x;
  __shared__ float cv[C];
  __shared__ float hid[MH];
  int t = threadIdx.x;
  if (t < C) cv[t] = ctx[bl * C + t];
  __syncthreads();
  if (t < MH) {
    float a = b1[t];
    for (int c2 = 0; c2 < C; ++c2) a += cv[c2] * w1[c2 * MH + t];
    hid[t] = tanhf(a);
  }
  __syncthreads();
  float scale = fscale[0];
  for (int k = t; k < F2; k += 256) {
    float a = b2[k];
    for (int j = 0; j < MH; ++j) a += hid[j] * w2[j * F2 + k];
    forcing[bl * F2 + k] = scale * a;
  }
}

// ---------------- encode ----------------
__global__ __launch_bounds__(256) void k_u(
    const float* __restrict__ x,
    const float* __restrict__ Vr, const float* __restrict__ Vi,
    const float* __restrict__ Ur, const float* __restrict__ Ui,
    const float* __restrict__ gam, const float* __restrict__ forcing,
    float* __restrict__ u) {
  int blc = blockIdx.x;
  int c = blc & (C - 1);
  __shared__ u32 xs_u[SW / 2];
  __shared__ u16 vtr[2][R][W + 2];
  __shared__ float y1[2][S * R];
  int t = threadIdx.x;
  {
    const float4* xp = (const float4*)(x + (size_t)blc * SW);
    for (int i = t; i < SW / 4; i += 256) {
      float4 v = xp[i];
      xs_u[i * 2]     = pack2(v.x, v.y);
      xs_u[i * 2 + 1] = pack2(v.z, v.w);
    }
  }
  {
    const float* vrp = Vr + (size_t)c * (W * R);
    const float* vip = Vi + (size_t)c * (W * R);
    for (int i = t; i < W * R; i += 256) {
      int w = i >> 5, r = i & 31;
      vtr[0][r][w] = f2bu(vrp[i]);
      vtr[1][r][w] = f2bu(vip[i]);
    }
  }
  __syncthreads();
  for (int p = t; p < S * R; p += 256) {
    int s = p >> 5, r = p & 31;
    const u32* xrow = xs_u + s * (W / 2);
    const u32* vrow_r = (const u32*)&vtr[0][r][0];
    const u32* vrow_i = (const u32*)&vtr[1][r][0];
    float ar = 0.f, ai = 0.f;
    for (int j = 0; j < W / 2; ++j) {
      u32 xv = xrow[j], vr = vrow_r[j], vi = vrow_i[j];
      float x0 = bf_lo(xv), x1 = bf_hi(xv);
      ar += x0 * bf_lo(vr) + x1 * bf_hi(vr);
      ai -= x0 * bf_lo(vi) + x1 * bf_hi(vi);
    }
    y1[0][p] = ar;
    y1[1][p] = ai;
  }
  __syncthreads();
  if (t < R) {
    int r = t;
    const float* urp = Ur + (size_t)c * (S * R);
    const float* uip = Ui + (size_t)c * (S * R);
    float sr = 0.f, si = 0.f;
    for (int s = 0; s < S; ++s) {
      float urv = urp[s * R + r];
      float uiv = uip[s * R + r];
      float yr = y1[0][s * R + r], yi = y1[1][s * R + r];
      sr += urv * yr + uiv * yi;
      si += urv * yi - uiv * yr;
    }
    float g = gam[c * R + r];
    float fr = forcing[(blc * R + r) * 2];
    float fi = forcing[(blc * R + r) * 2 + 1];
    float ofr = 1.f + fr;
    u[(blc * R + r) * 2]     = g * (sr * ofr - si * fi);
    u[(blc * R + r) * 2 + 1] = g * (sr * fi + si * ofr);
  }
}

// ---------------- diagonal scan over L ----------------
__global__ void k_scan(const float* __restrict__ lamr, const float* __restrict__ lami,
                       const float* __restrict__ u, float* __restrict__ h) {
  int i = blockIdx.x * 256 + threadIdx.x;
  if (i >= B * CR) return;
  int b = i / CR;
  int cr = i - b * CR;
  float lr = lamr[cr], li = lami[cr];
  float hr = 0.f, hi = 0.f;
  for (int l = 0; l < L; ++l) {
    size_t off = ((size_t)(b * L + l) * CR + cr) * 2;
    float ur = u[off], ui = u[off + 1];
    float nr = lr * hr - li * hi + ur;
    float ni = lr * hi + li * hr + ui;
    hr = nr; hi = ni;
    h[off] = hr; h[off + 1] = hi;
  }
}

// ---------------- MFMA decode: per (bl,c), Y[s,w] = (h*U)[s,:] x V[w,:]^T (complex via real-stack) ----------------
// Output y_cm32[(blh*64+c)*8192 + s*128 + w] = pack2(Yr, Yi)
__global__ __launch_bounds__(256) void k_decode(
    const float* __restrict__ h,
    const float* __restrict__ Ur, const float* __restrict__ Ui,
    const float* __restrict__ Vr, const float* __restrict__ Vi,
    u32* __restrict__ y_cm32, int bl_base) {
  int bid = blockIdx.x;
  int c = bid & 63;
  int blh = bid >> 6;
  int bl = bl_base + blh;
  __shared__ __align__(16) u16 ldA[64 * 72];    // A'[s][k], k<32: ar, k>=32: ai
  __shared__ __align__(16) u16 ldBr[128 * 72];  // Br[w][k]: Vr | -Vi
  __shared__ __align__(16) u16 ldBi[128 * 72];  // Bi[w][k]: Vi |  Vr
  int t = threadIdx.x;
  // build A' = h (*) U  (complex elementwise, no conj)
  {
    const float* hp = h + ((size_t)(bl * C + c) * R) * 2;
    const float* urp = Ur + (size_t)c * (S * R);
    const float* uip = Ui + (size_t)c * (S * R);
    for (int p = t; p < S * R; p += 256) {
      int s = p >> 5, r = p & 31;
      float hr = hp[r * 2], hi = hp[r * 2 + 1];
      float ur = urp[p], ui = uip[p];
      ldA[s * 72 + r]      = f2bu(hr * ur - hi * ui);
      ldA[s * 72 + 32 + r] = f2bu(hr * ui + hi * ur);
    }
  }
  // build B
  {
    const float* vrp = Vr + (size_t)c * (W * R);
    const float* vip = Vi + (size_t)c * (W * R);
    for (int p = t; p < W * R; p += 256) {
      int w = p >> 5, r = p & 31;
      float vr = vrp[p], vi = vip[p];
      ldBr[w * 72 + r]      = f2bu(vr);
      ldBr[w * 72 + 32 + r] = f2bu(-vi);
      ldBi[w * 72 + r]      = f2bu(vi);
      ldBi[w * 72 + 32 + r] = f2bu(vr);
    }
  }
  __syncthreads();
  int lane = t & 63, q = t >> 6;          // q = n-quarter (w block of 32)
  int quad = lane >> 4, l15 = lane & 15;
  f32x4 zf = {0.f, 0.f, 0.f, 0.f};
  f32x4 accr[4][2], acci[4][2];
#pragma unroll
  for (int mt = 0; mt < 4; ++mt)
#pragma unroll
    for (int nt = 0; nt < 2; ++nt) { accr[mt][nt] = zf; acci[mt][nt] = zf; }
#pragma unroll
  for (int ks = 0; ks < 2; ++ks) {
    int kofs = ks * 32 + quad * 8;
    short8 af[4];
#pragma unroll
    for (int mt = 0; mt < 4; ++mt)
      af[mt] = *(const short8*)&ldA[(mt * 16 + l15) * 72 + kofs];
#pragma unroll
    for (int nt = 0; nt < 2; ++nt) {
      int wrow = q * 32 + nt * 16 + l15;
      short8 br = *(const short8*)&ldBr[wrow * 72 + kofs];
      short8 bi = *(const short8*)&ldBi[wrow * 72 + kofs];
#pragma unroll
      for (int mt = 0; mt < 4; ++mt) {
        accr[mt][nt] = __builtin_amdgcn_mfma_f32_16x16x32_bf16(af[mt], br, accr[mt][nt], 0, 0, 0);
        acci[mt][nt] = __builtin_amdgcn_mfma_f32_16x16x32_bf16(af[mt], bi, acci[mt][nt], 0, 0, 0);
      }
    }
  }
  // C/D: row(s) = quad*4+reg, col(w) = l15
  u32* dst = y_cm32 + ((size_t)(blh * 64 + c) << 13);
#pragma unroll
  for (int mt = 0; mt < 4; ++mt) {
#pragma unroll
    for (int nt = 0; nt < 2; ++nt) {
      int w = q * 32 + nt * 16 + l15;
#pragma unroll
      for (int reg = 0; reg < 4; ++reg) {
        int s = mt * 16 + quad * 4 + reg;
        dst[s * 128 + w] = pack2(accr[mt][nt][reg], acci[mt][nt][reg]);
      }
    }
  }
}

// ---------------- MFMA projection GEMM: M=128 ch_out, K=128, N=512/block -> NHWC ----------------
__global__ __launch_bounds__(256) void k_proj(
    const u32* __restrict__ y_cm32, const u16* __restrict__ aproj,
    const float* __restrict__ pbr, const float* __restrict__ pbi,
    u16* __restrict__ ynhwc, int bl_base) {
  int bid = blockIdx.x;              // 16 bl x 16 ntiles
  int ntile = bid & 15;
  int blh = bid >> 4;
  int bl = bl_base + blh;
  __shared__ __align__(16) u16 lda[128 * 136];
  __shared__ __align__(16) u32 ldb[128 * 68];
  __shared__ float ldbias[128];
  int t = threadIdx.x;
  for (int i = t; i < 128 * 16; i += 256) {
    int m = i >> 4, qq = i & 15;
    ((uint4*)&lda[m * 136])[qq] = ((const uint4*)&aproj[m * 128])[qq];
  }
  if (t < 128) ldbias[t] = t < 64 ? pbr[t] : pbi[t - 64];

  int lane = t & 63, wv = t >> 6;
  int quad = lane >> 4, l15 = lane & 15;
  int cidx = t & 63, seg = t >> 6;
  f32x4 zf = {0.f, 0.f, 0.f, 0.f};

  for (int chunk = 0; chunk < 4; ++chunk) {
    int n0 = ntile * 512 + chunk * 128;
    __syncthreads();
    // stage B: thread (cidx, seg): copy y_cm32[blh][cidx][n0+seg*32 .. +32] -> ldb[n][cidx]
    {
      const uint4* src = (const uint4*)(y_cm32 + (((size_t)(blh * 64 + cidx)) << 13) + n0 + seg * 32);
      u32 tmp[32];
#pragma unroll
      for (int qq = 0; qq < 8; ++qq) {
        uint4 v = src[qq];
        tmp[qq * 4] = v.x; tmp[qq * 4 + 1] = v.y; tmp[qq * 4 + 2] = v.z; tmp[qq * 4 + 3] = v.w;
      }
#pragma unroll
      for (int j = 0; j < 32; ++j)
        ldb[(seg * 32 + j) * 68 + cidx] = tmp[j];
    }
    __syncthreads();
    // MFMA: wave wv handles n-tiles {2wv, 2wv+1}, all 8 m-tiles
    f32x4 acc[8][2];
#pragma unroll
    for (int mt = 0; mt < 8; ++mt) { acc[mt][0] = zf; acc[mt][1] = zf; }
    const u16* ldb16 = (const u16*)ldb;
#pragma unroll
    for (int ks = 0; ks < 4; ++ks) {
      int kofs = ks * 32 + quad * 8;
      short8 af[8];
#pragma unroll
      for (int mt = 0; mt < 8; ++mt)
        af[mt] = *(const short8*)&lda[(mt * 16 + l15) * 136 + kofs];
#pragma unroll
      for (int nt = 0; nt < 2; ++nt) {
        int nrow = wv * 32 + nt * 16 + l15;
        short8 bf = *(const short8*)&ldb16[nrow * 136 + kofs];
#pragma unroll
        for (int mt = 0; mt < 8; ++mt)
          acc[mt][nt] = __builtin_amdgcn_mfma_f32_16x16x32_bf16(af[mt], bf, acc[mt][nt], 0, 0, 0);
      }
    }
    // epilogue: direct NHWC stores; lane covers n = wv*32+nt*16+l15, ch = mt*16+quad*4..+3
#pragma unroll
    for (int nt = 0; nt < 2; ++nt) {
      int n = n0 + wv * 32 + nt * 16 + l15;
      u16* drow = ynhwc + (((size_t)bl * SW + n) << 7);
#pragma unroll
      for (int mt = 0; mt < 8; ++mt) {
        int ch = mt * 16 + quad * 4;
        u32 lo = pack2(acc[mt][nt][0] + ldbias[ch],     acc[mt][nt][1] + ldbias[ch + 1]);
        u32 hi = pack2(acc[mt][nt][2] + ldbias[ch + 2], acc[mt][nt][3] + ldbias[ch + 3]);
        u32* dp = (u32*)(drow + ch);
        dp[0] = lo; dp[1] = hi;
      }
    }
  }
}

// ---------------- MFMA implicit-GEMM conv (unchanged) ----------------
__global__ __launch_bounds__(256) void k_conv(
    const u16* __restrict__ ynhwc, const u16* __restrict__ keff_bf,
    const float* __restrict__ biaseff, u16* __restrict__ fused) {
  int bid = blockIdx.x;
  int wt = bid & 3;
  int st = (bid >> 2) & 31;
  int bl = bid >> 7;
  int s0 = st * 2;
  int w0 = wt * 32;
  __shared__ __align__(16) u16 win[4][34][136];
  int t = threadIdx.x;
  int c_lo = (w0 == 0) ? 1 : 0;
  int c_hi = (w0 == 96) ? 33 : 34;
  uint4 z4 = make_uint4(0u, 0u, 0u, 0u);
  for (int rr = 0; rr < 4; ++rr) {
    int rs = s0 - 1 + rr;
    if (rs < 0 || rs >= S) {
      uint4* wrow = (uint4*)&win[rr][0][0];
      for (int i = t; i < 578; i += 256) wrow[i] = z4;
    } else {
      if (w0 == 0 && t < 16) ((uint4*)&win[rr][0][0])[t] = z4;
      if (w0 == 96 && t < 16) ((uint4*)&win[rr][33][0])[t] = z4;
      const uint4* src = (const uint4*)(ynhwc + (((size_t)bl * S + rs) * W + (w0 - 1 + c_lo)) * 128);
      int n4 = (c_hi - c_lo) * 16;
      for (int i = t; i < n4; i += 256) {
        int col = i >> 4, q = i & 15;
        ((uint4*)&win[rr][c_lo + col][0])[q] = src[i];
      }
    }
  }
  __syncthreads();

  int lane = t & 63;
  int wv = t >> 6;
  int mp = wv & 1;
  int np = wv >> 1;
  int quad = lane >> 4, l15 = lane & 15;
  int chq = quad * 8;

  f32x4 zf = {0.f, 0.f, 0.f, 0.f};
  f32x4 acc00 = zf, acc01 = zf, acc10 = zf, acc11 = zf;
  const short8* ap = (const short8*)keff_bf;

  for (int seg = 0; seg < 9; ++seg) {
    int dr = seg / 3;
    int dc = seg - dr * 3;
    const u16* b0base = &win[np + dr][l15 + dc][chq];
    const u16* b1base = b0base + 16 * 136;
#pragma unroll
    for (int ks = 0; ks < 4; ++ks) {
      short8 a0 = ap[((seg * 4 + ks) * 4 + 2 * mp) * 64 + lane];
      short8 a1 = ap[((seg * 4 + ks) * 4 + 2 * mp + 1) * 64 + lane];
      short8 b0 = *(const short8*)(b0base + ks * 32);
      short8 b1 = *(const short8*)(b1base + ks * 32);
      acc00 = __builtin_amdgcn_mfma_f32_16x16x32_bf16(a0, b0, acc00, 0, 0, 0);
      acc01 = __builtin_amdgcn_mfma_f32_16x16x32_bf16(a0, b1, acc01, 0, 0, 0);
      acc10 = __builtin_amdgcn_mfma_f32_16x16x32_bf16(a1, b0, acc10, 0, 0, 0);
      acc11 = __builtin_amdgcn_mfma_f32_16x16x32_bf16(a1, b1, acc11, 0, 0, 0);
    }
  }

  int s_out = s0 + np;
#pragma unroll
  for (int mi = 0; mi < 2; ++mi) {
    f32x4 aN0 = mi ? acc10 : acc00;
    f32x4 aN1 = mi ? acc11 : acc01;
#pragma unroll
    for (int reg = 0; reg < 4; ++reg) {
      int o = (2 * mp + mi) * 16 + quad * 4 + reg;
      float bias = biaseff[o];
      size_t rowoff = ((size_t)(bl * C + o) * S + s_out) * W;
      fused[rowoff + w0 + l15]      = f2bu(aN0[reg] + bias);
      fused[rowoff + w0 + 16 + l15] = f2bu(aN1[reg] + bias);
    }
  }
}

// ---------------- layernorm (stats in-kernel) + residual ----------------
__global__ __launch_bounds__(256) void k_ln(
    const u16* __restrict__ fused,
    const float* __restrict__ ln_g, const float* __restrict__ ln_b,
    const float* __restrict__ x, float* __restrict__ out) {
  int blc = blockIdx.x;
  __shared__ u16 fs[SW];
  __shared__ float red[12];
  int t = threadIdx.x;
  const uint4* fp = (const uint4*)(fused + (size_t)blc * SW);
  float sm = 0.f, sq = 0.f;
  for (int i = t; i < SW / 8; i += 256) {
    uint4 v = fp[i];
    ((uint4*)fs)[i] = v;
    float f0 = bf_lo(v.x), f1 = bf_hi(v.x), f2 = bf_lo(v.y), f3 = bf_hi(v.y);
    float f4 = bf_lo(v.z), f5 = bf_hi(v.z), f6 = bf_lo(v.w), f7 = bf_hi(v.w);
    sm += f0 + f1 + f2 + f3 + f4 + f5 + f6 + f7;
    sq += f0 * f0 + f1 * f1 + f2 * f2 + f3 * f3 + f4 * f4 + f5 * f5 + f6 * f6 + f7 * f7;
  }
#pragma unroll
  for (int off = 32; off > 0; off >>= 1) {
    sm += __shfl_down(sm, off, 64);
    sq += __shfl_down(sq, off, 64);
  }
  int lane = t & 63, wid = t >> 6;
  if (lane == 0) { red[wid * 2] = sm; red[wid * 2 + 1] = sq; }
  __syncthreads();
  if (t == 0) {
    float S1 = red[0] + red[2] + red[4] + red[6];
    float S2 = red[1] + red[3] + red[5] + red[7];
    float mu = S1 * (1.f / SW);
    float var = S2 * (1.f / SW) - mu * mu;
    red[8] = mu;
    red[9] = rsqrtf(var + 1e-5f);
  }
  __syncthreads();
  float mu = red[8], rstd = red[9];
  const float* xp = x + (size_t)blc * SW;
  float* op = out + (size_t)blc * SW;
  for (int i = t; i < SW; i += 256)
    op[i] = (us2f(fs[i]) - mu) * rstd * ln_g[i] + ln_b[i] + xp[i];
}

extern "C" void kernel_launch(void* const* d_in, const int* in_sizes, int n_in,
                              void* d_out, int out_size, void* d_ws, size_t ws_size,
                              hipStream_t stream) {
  (void)in_sizes; (void)n_in; (void)out_size; (void)ws_size;
  const float* x       = (const float*)d_in[0];
  const float* nu_log  = (const float*)d_in[1];
  const float* th_log  = (const float*)d_in[2];
  const float* dnu     = (const float*)d_in[3];
  const float* dth     = (const float*)d_in[4];
  const float* w1      = (const float*)d_in[5];
  const float* b1      = (const float*)d_in[6];
  const float* w2      = (const float*)d_in[7];
  const float* b2      = (const float*)d_in[8];
  const float* fscale  = (const float*)d_in[9];
  const float* Ur      = (const float*)d_in[10];
  const float* Ui      = (const float*)d_in[11];
  const float* Vr      = (const float*)d_in[12];
  const float* Vi      = (const float*)d_in[13];
  const float* pWr     = (const float*)d_in[14];
  const float* pWi     = (const float*)d_in[15];
  const float* pbr     = (const float*)d_in[16];
  const float* pbi     = (const float*)d_in[17];
  const float* convr_k = (const float*)d_in[18];
  const float* convr_b = (const float*)d_in[19];
  const float* convi_k = (const float*)d_in[20];
  const float* convi_b = (const float*)d_in[21];
  const float* fuse_k  = (const float*)d_in[22];
  const float* fuse_b  = (const float*)d_in[23];
  const float* ln_g    = (const float*)d_in[24];
  const float* ln_b    = (const float*)d_in[25];
  float* out = (float*)d_out;

  char* ws = (char*)d_ws;
  float* lamr    = (float*)ws;
  float* lami    = lamr + 2048;
  float* gam     = lami + 2048;
  float* biaseff = gam + 2048;        // 64
  float* ctx     = biaseff + 64;      // 2048
  float* forcing = ctx + 2048;        // 131072
  float* ubuf    = forcing + 131072;  // 131072
  float* hbuf    = ubuf + 131072;     // 131072
  u16* keff_bf   = (u16*)(hbuf + 131072);       // 73728 u16 (144 KB)
  u16* aproj     = keff_bf + 73728;             // 16384 u16 (32 KB)
  // align to 256 B
  size_t off = ((size_t)((char*)(aproj + 16384) - ws) + 255) & ~(size_t)255;
  u32* y_cm32    = (u32*)(ws + off);            // 16*64*8192 u32 = 32 MB (half-batch)
  u16* fused     = (u16*)y_cm32;                // ALIAS: 32 MB, live only after y_cm32 dead
  u16* ynhwc     = (u16*)(ws + off + (size_t)32 * 1024 * 1024);  // 64 MB
  // total ws ~ 97.8 MB

  k_prep<<<8, 256, 0, stream>>>(nu_log, th_log, dnu, dth, lamr, lami, gam);
  k_keff<<<289, 256, 0, stream>>>(fuse_k, fuse_b, convr_k, convr_b, convi_k, convi_b,
                                  keff_bf, biaseff);
  k_apack<<<64, 256, 0, stream>>>(pWr, pWi, aproj);
  k_ctx<<<BL * C, 256, 0, stream>>>(x, ctx);
  k_mlp<<<BL, 256, 0, stream>>>(ctx, w1, b1, w2, b2, fscale, forcing);
  k_u<<<BL * C, 256, 0, stream>>>(x, Vr, Vi, Ur, Ui, gam, forcing, ubuf);
  k_scan<<<16, 256, 0, stream>>>(lamr, lami, ubuf, hbuf);
  // decode+project in two bl-halves (y_cm32 is half-sized)
  k_decode<<<1024, 256, 0, stream>>>(hbuf, Ur, Ui, Vr, Vi, y_cm32, 0);
  k_proj<<<256, 256, 0, stream>>>(y_cm32, aproj, pbr, pbi, ynhwc, 0);
  k_decode<<<1024, 256, 0, stream>>>(hbuf, Ur, Ui, Vr, Vi, y_cm32, 16);
  k_proj<<<256, 256, 0, stream>>>(y_cm32, aproj, pbr, pbi, ynhwc, 16);
  k_conv<<<4096, 256, 0, stream>>>(ynhwc, keff_bf, biaseff, fused);
  k_ln<<<BL * C, 256, 0, stream>>>(fused, ln_g, ln_b, x, out);
}

// Round 5
// 447.399 us; speedup vs baseline: 4.7091x; 1.1731x over previous
//
#include <hip/hip_runtime.h>

typedef unsigned short u16;
typedef unsigned int u32;
typedef __attribute__((ext_vector_type(8))) short short8;
typedef __attribute__((ext_vector_type(4))) float f32x4;

constexpr int B = 2, L = 16, C = 64, S = 64, W = 128, R = 32, MH = 32;
constexpr int BL = B * L;        // 32
constexpr int SW = S * W;        // 8192
constexpr int CR = C * R;        // 2048
constexpr int F2 = C * R * 2;    // 4096

__device__ __forceinline__ float us2f(u16 h) { return __uint_as_float(((u32)h) << 16); }
__device__ __forceinline__ float bf_lo(u32 u) { return __uint_as_float(u << 16); }
__device__ __forceinline__ float bf_hi(u32 u) { return __uint_as_float(u & 0xffff0000u); }
__device__ __forceinline__ u16 f2bu(float f) {
  u32 u = __float_as_uint(f);
  u32 r = (u + 0x7fffu + ((u >> 16) & 1u)) >> 16;
  return (u16)r;
}
__device__ __forceinline__ u32 pack2(float lo, float hi) {
  return (u32)f2bu(lo) | ((u32)f2bu(hi) << 16);
}

// ---------------- prep: lam, gamma ----------------
__global__ void k_prep(const float* __restrict__ nu_log, const float* __restrict__ th_log,
                       const float* __restrict__ dnu, const float* __restrict__ dth,
                       float* __restrict__ lamr, float* __restrict__ lami,
                       float* __restrict__ gam) {
  int i = blockIdx.x * 256 + threadIdx.x;
  if (i >= CR) return;
  float nu = expf(nu_log[i] + dnu[i]);
  float th = expf(th_log[i] + dth[i]);
  float mag = expf(-nu);
  lamr[i] = mag * cosf(th);
  lami[i] = mag * sinf(th);
  gam[i] = sqrtf(fmaxf(1.0f - mag * mag, 1e-6f));
}

// ---------------- prep: effective conv kernel (fuse folded), MFMA-A-swizzled bf16 ----------------
__global__ void k_keff(const float* __restrict__ fuse_k, const float* __restrict__ fuse_b,
                       const float* __restrict__ convr_k, const float* __restrict__ convr_b,
                       const float* __restrict__ convi_k, const float* __restrict__ convi_b,
                       u16* __restrict__ keff_bf, float* __restrict__ biaseff) {
  int i = blockIdx.x * 256 + threadIdx.x;
  if (i < C * 2 * C * 9) {
    int o = i / (2 * C * 9);
    int rem = i - o * (2 * C * 9);
    int cin2 = rem / 9;
    int seg = rem - cin2 * 9;
    const float* ck = (cin2 < C) ? convr_k : convi_k;
    int cin = cin2 & (C - 1);
    int fbase = o * 2 * C + ((cin2 < C) ? 0 : C);
    float acc = 0.f;
    for (int m = 0; m < C; ++m)
      acc += fuse_k[fbase + m] * ck[(m * C + cin) * 9 + seg];
    int kstep = cin2 >> 5;
    int kk = cin2 & 31;
    int lane = (o & 15) | ((kk >> 3) << 4);
    int j = kk & 7;
    int m_tile = o >> 4;
    keff_bf[((((seg * 4 + kstep) * 4 + m_tile) * 64 + lane) << 3) + j] = f2bu(acc);
  } else if (i < C * 2 * C * 9 + C) {
    int o = i - C * 2 * C * 9;
    float acc = fuse_b[o];
    for (int m = 0; m < C; ++m) {
      acc += fuse_k[o * 2 * C + m] * convr_b[m];
      acc += fuse_k[o * 2 * C + C + m] * convi_b[m];
    }
    biaseff[o] = acc;
  }
}

// ---------------- prep: projection matrix real-stacked bf16 [m=128][k=128] ----------------
__global__ void k_apack(const float* __restrict__ pWr, const float* __restrict__ pWi,
                        u16* __restrict__ aproj) {
  int i = blockIdx.x * 256 + threadIdx.x;
  if (i >= 128 * 128) return;
  int m = i >> 7, k = i & 127;
  int c = k >> 1, im = k & 1;
  int o = m & 63;
  float v;
  if (m < 64) v = im ? -pWi[o * 64 + c] : pWr[o * 64 + c];
  else        v = im ?  pWr[o * 64 + c] : pWi[o * 64 + c];
  aproj[i] = f2bu(v);
}

// ---------------- MLP -> forcing ----------------
__global__ __launch_bounds__(256) void k_mlp(
    const float* __restrict__ ctx, const float* __restrict__ w1, const float* __restrict__ b1,
    const float* __restrict__ w2, const float* __restrict__ b2, const float* __restrict__ fscale,
    float* __restrict__ forcing) {
  int bl = blockIdx.x;
  __shared__ float cv[C];
  __shared__ float hid[MH];
  int t = threadIdx.x;
  if (t < C) cv[t] = ctx[bl * C + t];
  __syncthreads();
  if (t < MH) {
    float a = b1[t];
    for (int c2 = 0; c2 < C; ++c2) a += cv[c2] * w1[c2 * MH + t];
    hid[t] = tanhf(a);
  }
  __syncthreads();
  float scale = fscale[0];
  for (int k = t; k < F2; k += 256) {
    float a = b2[k];
    for (int j = 0; j < MH; ++j) a += hid[j] * w2[j * F2 + k];
    forcing[bl * F2 + k] = scale * a;
  }
}

// ---------------- MFMA encode (+ ctx fused): per (b,l,c) block ----------------
// y1[s][n] = sum_w x[s,w]*B[n][w];  B rows: n<32 -> Vr[c,w,n] (real), n>=32 -> -Vi (imag, conj)
// then u_raw[r] = sum_s conj(U[c,s,r]) * (y1[s][r] + i*y1[s][32+r])
__global__ __launch_bounds__(256) void k_enc(
    const float* __restrict__ x,
    const float* __restrict__ Vr, const float* __restrict__ Vi,
    const float* __restrict__ Ur, const float* __restrict__ Ui,
    float* __restrict__ ctx, float* __restrict__ u) {
  int blc = blockIdx.x;
  int c = blc & (C - 1);
  __shared__ __align__(16) char smem[17408 * 2 + 16384 + 64];
  u16* xt = (u16*)smem;                    // [64][136] A = x[s][w] bf16
  u16* bt = (u16*)(smem + 17408);          // [64][136] B rows
  float* uldr = (float*)(smem + 34816);    // [2048] U real [s*32+r]
  float* uldi = uldr + 2048;               // [2048] U imag
  float* y1  = (float*)smem;               // alias xt: [64][65] f32 (16640 B)
  float* part = (float*)(smem + 17408);    // alias bt: [8][64]
  float* red = (float*)(smem + 17408 * 2 + 16384);  // [16]
  int t = threadIdx.x;
  int lane = t & 63, wv = t >> 6;
  // stage x (f32 -> bf16 LDS) + ctx sum
  float sm = 0.f;
  {
    const float4* xp = (const float4*)(x + (size_t)blc * SW);
    for (int i = t; i < SW / 4; i += 256) {
      float4 v = xp[i];
      sm += v.x + v.y + v.z + v.w;
      int idx = i * 4, s = idx >> 7, w = idx & 127;
      u32* d = (u32*)&xt[s * 136 + w];
      d[0] = pack2(v.x, v.y);
      d[1] = pack2(v.z, v.w);
    }
  }
#pragma unroll
  for (int o = 32; o > 0; o >>= 1) sm += __shfl_down(sm, o, 64);
  if (lane == 0) red[wv] = sm;
  // stage B = [Vr ; -Vi]
  {
    const float* vrp = Vr + (size_t)c * 4096;
    const float* vip = Vi + (size_t)c * 4096;
    for (int i = t; i < 4096; i += 256) {
      int w = i >> 5, r = i & 31;
      bt[r * 136 + w]        = f2bu(vrp[i]);
      bt[(32 + r) * 136 + w] = f2bu(-vip[i]);
    }
  }
  // stage U f32
  {
    const float* urp = Ur + (size_t)c * 2048;
    const float* uip = Ui + (size_t)c * 2048;
    for (int i = t; i < 2048; i += 256) { uldr[i] = urp[i]; uldi[i] = uip[i]; }
  }
  __syncthreads();
  if (t == 0) ctx[blc] = (red[0] + red[1] + red[2] + red[3]) * (1.f / SW);
  // MFMA: wave wv = n-tile; acc over 4 m-tiles
  int quad = lane >> 4, l15 = lane & 15;
  f32x4 zf = {0.f, 0.f, 0.f, 0.f};
  f32x4 acc[4] = {zf, zf, zf, zf};
#pragma unroll
  for (int ks = 0; ks < 4; ++ks) {
    int kofs = ks * 32 + quad * 8;
    short8 bf = *(const short8*)&bt[(wv * 16 + l15) * 136 + kofs];
#pragma unroll
    for (int mt = 0; mt < 4; ++mt) {
      short8 af = *(const short8*)&xt[(mt * 16 + l15) * 136 + kofs];
      acc[mt] = __builtin_amdgcn_mfma_f32_16x16x32_bf16(af, bf, acc[mt], 0, 0, 0);
    }
  }
  __syncthreads();   // xt/bt reads done
  // write y1 C-frags: s = mt*16+quad*4+reg, n = wv*16+l15
#pragma unroll
  for (int mt = 0; mt < 4; ++mt)
#pragma unroll
    for (int reg = 0; reg < 4; ++reg)
      y1[(mt * 16 + quad * 4 + reg) * 65 + wv * 16 + l15] = acc[mt][reg];
  __syncthreads();
  // stage 2: u_raw[r] = sum_s conj(U[s,r]) * y1[s,r]
  {
    int r = t & 31, sg = t >> 5;
    float pr = 0.f, pi = 0.f;
#pragma unroll
    for (int k = 0; k < 8; ++k) {
      int s = sg * 8 + k;
      float yr = y1[s * 65 + r], yi = y1[s * 65 + 32 + r];
      float ur = uldr[s * 32 + r], ui = uldi[s * 32 + r];
      pr += ur * yr + ui * yi;
      pi += ur * yi - ui * yr;
    }
    part[sg * 64 + r * 2]     = pr;
    part[sg * 64 + r * 2 + 1] = pi;
  }
  __syncthreads();
  if (t < 32) {
    float pr = 0.f, pi = 0.f;
#pragma unroll
    for (int sg = 0; sg < 8; ++sg) {
      pr += part[sg * 64 + t * 2];
      pi += part[sg * 64 + t * 2 + 1];
    }
    u[((size_t)blc * R + t) * 2]     = pr;
    u[((size_t)blc * R + t) * 2 + 1] = pi;
  }
}

// ---------------- diagonal scan over L (applies gamma*(1+forcing)) ----------------
__global__ void k_scan(const float* __restrict__ lamr, const float* __restrict__ lami,
                       const float* __restrict__ gam, const float* __restrict__ forcing,
                       const float* __restrict__ u, float* __restrict__ h) {
  int i = blockIdx.x * 256 + threadIdx.x;
  if (i >= B * CR) return;
  int b = i / CR;
  int cr = i - b * CR;
  float lr = lamr[cr], li = lami[cr], g = gam[cr];
  float hr = 0.f, hi = 0.f;
  for (int l = 0; l < L; ++l) {
    size_t off = ((size_t)(b * L + l) * CR + cr) * 2;
    float ur0 = u[off], ui0 = u[off + 1];
    float fr = forcing[off], fi = forcing[off + 1];
    float ofr = 1.f + fr;
    float ur = g * (ur0 * ofr - ui0 * fi);
    float ui = g * (ur0 * fi + ui0 * ofr);
    float nr = lr * hr - li * hi + ur;
    float ni = lr * hi + li * hr + ui;
    hr = nr; hi = ni;
    h[off] = hr; h[off + 1] = hi;
  }
}

// ---------------- MFMA decode: per (bl,c), Y[s,w] = (h*U)[s,:] x V[w,:]^T ----------------
__global__ __launch_bounds__(256) void k_decode(
    const float* __restrict__ h,
    const float* __restrict__ Ur, const float* __restrict__ Ui,
    const float* __restrict__ Vr, const float* __restrict__ Vi,
    u32* __restrict__ y_cm32, int bl_base) {
  int bid = blockIdx.x;
  int c = bid & 63;
  int blh = bid >> 6;
  int bl = bl_base + blh;
  __shared__ __align__(16) u16 ldA[64 * 72];
  __shared__ __align__(16) u16 ldBr[128 * 72];
  __shared__ __align__(16) u16 ldBi[128 * 72];
  int t = threadIdx.x;
  {
    const float* hp = h + ((size_t)(bl * C + c) * R) * 2;
    const float* urp = Ur + (size_t)c * (S * R);
    const float* uip = Ui + (size_t)c * (S * R);
    for (int p = t; p < S * R; p += 256) {
      int s = p >> 5, r = p & 31;
      float hr = hp[r * 2], hi = hp[r * 2 + 1];
      float ur = urp[p], ui = uip[p];
      ldA[s * 72 + r]      = f2bu(hr * ur - hi * ui);
      ldA[s * 72 + 32 + r] = f2bu(hr * ui + hi * ur);
    }
  }
  {
    const float* vrp = Vr + (size_t)c * (W * R);
    const float* vip = Vi + (size_t)c * (W * R);
    for (int p = t; p < W * R; p += 256) {
      int w = p >> 5, r = p & 31;
      float vr = vrp[p], vi = vip[p];
      ldBr[w * 72 + r]      = f2bu(vr);
      ldBr[w * 72 + 32 + r] = f2bu(-vi);
      ldBi[w * 72 + r]      = f2bu(vi);
      ldBi[w * 72 + 32 + r] = f2bu(vr);
    }
  }
  __syncthreads();
  int lane = t & 63, q = t >> 6;
  int quad = lane >> 4, l15 = lane & 15;
  f32x4 zf = {0.f, 0.f, 0.f, 0.f};
  f32x4 accr[4][2], acci[4][2];
#pragma unroll
  for (int mt = 0; mt < 4; ++mt)
#pragma unroll
    for (int nt = 0; nt < 2; ++nt) { accr[mt][nt] = zf; acci[mt][nt] = zf; }
#pragma unroll
  for (int ks = 0; ks < 2; ++ks) {
    int kofs = ks * 32 + quad * 8;
    short8 af[4];
#pragma unroll
    for (int mt = 0; mt < 4; ++mt)
      af[mt] = *(const short8*)&ldA[(mt * 16 + l15) * 72 + kofs];
#pragma unroll
    for (int nt = 0; nt < 2; ++nt) {
      int wrow = q * 32 + nt * 16 + l15;
      short8 br = *(const short8*)&ldBr[wrow * 72 + kofs];
      short8 bi = *(const short8*)&ldBi[wrow * 72 + kofs];
#pragma unroll
      for (int mt = 0; mt < 4; ++mt) {
        accr[mt][nt] = __builtin_amdgcn_mfma_f32_16x16x32_bf16(af[mt], br, accr[mt][nt], 0, 0, 0);
        acci[mt][nt] = __builtin_amdgcn_mfma_f32_16x16x32_bf16(af[mt], bi, acci[mt][nt], 0, 0, 0);
      }
    }
  }
  u32* dst = y_cm32 + ((size_t)(blh * 64 + c) << 13);
#pragma unroll
  for (int mt = 0; mt < 4; ++mt) {
#pragma unroll
    for (int nt = 0; nt < 2; ++nt) {
      int w = q * 32 + nt * 16 + l15;
#pragma unroll
      for (int reg = 0; reg < 4; ++reg) {
        int s = mt * 16 + quad * 4 + reg;
        dst[s * 128 + w] = pack2(accr[mt][nt][reg], acci[mt][nt][reg]);
      }
    }
  }
}

// ---------------- MFMA projection GEMM: M=128 ch_out, K=128, N=512/block -> NHWC ----------------
__global__ __launch_bounds__(256) void k_proj(
    const u32* __restrict__ y_cm32, const u16* __restrict__ aproj,
    const float* __restrict__ pbr, const float* __restrict__ pbi,
    u16* __restrict__ ynhwc, int bl_base) {
  int bid = blockIdx.x;
  int ntile = bid & 15;
  int blh = bid >> 4;
  int bl = bl_base + blh;
  __shared__ __align__(16) u16 lda[128 * 136];
  __shared__ __align__(16) u32 ldb[128 * 68];
  __shared__ float ldbias[128];
  int t = threadIdx.x;
  for (int i = t; i < 128 * 16; i += 256) {
    int m = i >> 4, qq = i & 15;
    ((uint4*)&lda[m * 136])[qq] = ((const uint4*)&aproj[m * 128])[qq];
  }
  if (t < 128) ldbias[t] = t < 64 ? pbr[t] : pbi[t - 64];

  int lane = t & 63, wv = t >> 6;
  int quad = lane >> 4, l15 = lane & 15;
  int cidx = t & 63, seg = t >> 6;
  f32x4 zf = {0.f, 0.f, 0.f, 0.f};

  for (int chunk = 0; chunk < 4; ++chunk) {
    int n0 = ntile * 512 + chunk * 128;
    __syncthreads();
    {
      const uint4* src = (const uint4*)(y_cm32 + (((size_t)(blh * 64 + cidx)) << 13) + n0 + seg * 32);
      u32 tmp[32];
#pragma unroll
      for (int qq = 0; qq < 8; ++qq) {
        uint4 v = src[qq];
        tmp[qq * 4] = v.x; tmp[qq * 4 + 1] = v.y; tmp[qq * 4 + 2] = v.z; tmp[qq * 4 + 3] = v.w;
      }
#pragma unroll
      for (int j = 0; j < 32; ++j)
        ldb[(seg * 32 + j) * 68 + cidx] = tmp[j];
    }
    __syncthreads();
    f32x4 acc[8][2];
#pragma unroll
    for (int mt = 0; mt < 8; ++mt) { acc[mt][0] = zf; acc[mt][1] = zf; }
    const u16* ldb16 = (const u16*)ldb;
#pragma unroll
    for (int ks = 0; ks < 4; ++ks) {
      int kofs = ks * 32 + quad * 8;
      short8 af[8];
#pragma unroll
      for (int mt = 0; mt < 8; ++mt)
        af[mt] = *(const short8*)&lda[(mt * 16 + l15) * 136 + kofs];
#pragma unroll
      for (int nt = 0; nt < 2; ++nt) {
        int nrow = wv * 32 + nt * 16 + l15;
        short8 bf = *(const short8*)&ldb16[nrow * 136 + kofs];
#pragma unroll
        for (int mt = 0; mt < 8; ++mt)
          acc[mt][nt] = __builtin_amdgcn_mfma_f32_16x16x32_bf16(af[mt], bf, acc[mt][nt], 0, 0, 0);
      }
    }
#pragma unroll
    for (int nt = 0; nt < 2; ++nt) {
      int n = n0 + wv * 32 + nt * 16 + l15;
      u16* drow = ynhwc + (((size_t)bl * SW + n) << 7);
#pragma unroll
      for (int mt = 0; mt < 8; ++mt) {
        int ch = mt * 16 + quad * 4;
        u32 lo = pack2(acc[mt][nt][0] + ldbias[ch],     acc[mt][nt][1] + ldbias[ch + 1]);
        u32 hi = pack2(acc[mt][nt][2] + ldbias[ch + 2], acc[mt][nt][3] + ldbias[ch + 3]);
        u32* dp = (u32*)(drow + ch);
        dp[0] = lo; dp[1] = hi;
      }
    }
  }
}

// ---------------- MFMA implicit-GEMM conv ----------------
__global__ __launch_bounds__(256) void k_conv(
    const u16* __restrict__ ynhwc, const u16* __restrict__ keff_bf,
    const float* __restrict__ biaseff, u16* __restrict__ fused) {
  int bid = blockIdx.x;
  int wt = bid & 3;
  int st = (bid >> 2) & 31;
  int bl = bid >> 7;
  int s0 = st * 2;
  int w0 = wt * 32;
  __shared__ __align__(16) u16 win[4][34][136];
  int t = threadIdx.x;
  int c_lo = (w0 == 0) ? 1 : 0;
  int c_hi = (w0 == 96) ? 33 : 34;
  uint4 z4 = make_uint4(0u, 0u, 0u, 0u);
  for (int rr = 0; rr < 4; ++rr) {
    int rs = s0 - 1 + rr;
    if (rs < 0 || rs >= S) {
      uint4* wrow = (uint4*)&win[rr][0][0];
      for (int i = t; i < 578; i += 256) wrow[i] = z4;
    } else {
      if (w0 == 0 && t < 16) ((uint4*)&win[rr][0][0])[t] = z4;
      if (w0 == 96 && t < 16) ((uint4*)&win[rr][33][0])[t] = z4;
      const uint4* src = (const uint4*)(ynhwc + (((size_t)bl * S + rs) * W + (w0 - 1 + c_lo)) * 128);
      int n4 = (c_hi - c_lo) * 16;
      for (int i = t; i < n4; i += 256) {
        int col = i >> 4, q = i & 15;
        ((uint4*)&win[rr][c_lo + col][0])[q] = src[i];
      }
    }
  }
  __syncthreads();

  int lane = t & 63;
  int wv = t >> 6;
  int mp = wv & 1;
  int np = wv >> 1;
  int quad = lane >> 4, l15 = lane & 15;
  int chq = quad * 8;

  f32x4 zf = {0.f, 0.f, 0.f, 0.f};
  f32x4 acc00 = zf, acc01 = zf, acc10 = zf, acc11 = zf;
  const short8* ap = (const short8*)keff_bf;

  for (int seg = 0; seg < 9; ++seg) {
    int dr = seg / 3;
    int dc = seg - dr * 3;
    const u16* b0base = &win[np + dr][l15 + dc][chq];
    const u16* b1base = b0base + 16 * 136;
#pragma unroll
    for (int ks = 0; ks < 4; ++ks) {
      short8 a0 = ap[((seg * 4 + ks) * 4 + 2 * mp) * 64 + lane];
      short8 a1 = ap[((seg * 4 + ks) * 4 + 2 * mp + 1) * 64 + lane];
      short8 b0 = *(const short8*)(b0base + ks * 32);
      short8 b1 = *(const short8*)(b1base + ks * 32);
      acc00 = __builtin_amdgcn_mfma_f32_16x16x32_bf16(a0, b0, acc00, 0, 0, 0);
      acc01 = __builtin_amdgcn_mfma_f32_16x16x32_bf16(a0, b1, acc01, 0, 0, 0);
      acc10 = __builtin_amdgcn_mfma_f32_16x16x32_bf16(a1, b0, acc10, 0, 0, 0);
      acc11 = __builtin_amdgcn_mfma_f32_16x16x32_bf16(a1, b1, acc11, 0, 0, 0);
    }
  }

  int s_out = s0 + np;
#pragma unroll
  for (int mi = 0; mi < 2; ++mi) {
    f32x4 aN0 = mi ? acc10 : acc00;
    f32x4 aN1 = mi ? acc11 : acc01;
#pragma unroll
    for (int reg = 0; reg < 4; ++reg) {
      int o = (2 * mp + mi) * 16 + quad * 4 + reg;
      float bias = biaseff[o];
      size_t rowoff = ((size_t)(bl * C + o) * S + s_out) * W;
      fused[rowoff + w0 + l15]      = f2bu(aN0[reg] + bias);
      fused[rowoff + w0 + 16 + l15] = f2bu(aN1[reg] + bias);
    }
  }
}

// ---------------- layernorm (stats in-kernel) + residual ----------------
__global__ __launch_bounds__(256) void k_ln(
    const u16* __restrict__ fused,
    const float* __restrict__ ln_g, const float* __restrict__ ln_b,
    const float* __restrict__ x, float* __restrict__ out) {
  int blc = blockIdx.x;
  __shared__ u16 fs[SW];
  __shared__ float red[12];
  int t = threadIdx.x;
  const uint4* fp = (const uint4*)(fused + (size_t)blc * SW);
  float sm = 0.f, sq = 0.f;
  for (int i = t; i < SW / 8; i += 256) {
    uint4 v = fp[i];
    ((uint4*)fs)[i] = v;
    float f0 = bf_lo(v.x), f1 = bf_hi(v.x), f2 = bf_lo(v.y), f3 = bf_hi(v.y);
    float f4 = bf_lo(v.z), f5 = bf_hi(v.z), f6 = bf_lo(v.w), f7 = bf_hi(v.w);
    sm += f0 + f1 + f2 + f3 + f4 + f5 + f6 + f7;
    sq += f0 * f0 + f1 * f1 + f2 * f2 + f3 * f3 + f4 * f4 + f5 * f5 + f6 * f6 + f7 * f7;
  }
#pragma unroll
  for (int off = 32; off > 0; off >>= 1) {
    sm += __shfl_down(sm, off, 64);
    sq += __shfl_down(sq, off, 64);
  }
  int lane = t & 63, wid = t >> 6;
  if (lane == 0) { red[wid * 2] = sm; red[wid * 2 + 1] = sq; }
  __syncthreads();
  if (t == 0) {
    float S1 = red[0] + red[2] + red[4] + red[6];
    float S2 = red[1] + red[3] + red[5] + red[7];
    float mu = S1 * (1.f / SW);
    float var = S2 * (1.f / SW) - mu * mu;
    red[8] = mu;
    red[9] = rsqrtf(var + 1e-5f);
  }
  __syncthreads();
  float mu = red[8], rstd = red[9];
  const float* xp = x + (size_t)blc * SW;
  float* op = out + (size_t)blc * SW;
  for (int i = t; i < SW; i += 256)
    op[i] = (us2f(fs[i]) - mu) * rstd * ln_g[i] + ln_b[i] + xp[i];
}

extern "C" void kernel_launch(void* const* d_in, const int* in_sizes, int n_in,
                              void* d_out, int out_size, void* d_ws, size_t ws_size,
                              hipStream_t stream) {
  (void)in_sizes; (void)n_in; (void)out_size; (void)ws_size;
  const float* x       = (const float*)d_in[0];
  const float* nu_log  = (const float*)d_in[1];
  const float* th_log  = (const float*)d_in[2];
  const float* dnu     = (const float*)d_in[3];
  const float* dth     = (const float*)d_in[4];
  const float* w1      = (const float*)d_in[5];
  const float* b1      = (const float*)d_in[6];
  const float* w2      = (const float*)d_in[7];
  const float* b2      = (const float*)d_in[8];
  const float* fscale  = (const float*)d_in[9];
  const float* Ur      = (const float*)d_in[10];
  const float* Ui      = (const float*)d_in[11];
  const float* Vr      = (const float*)d_in[12];
  const float* Vi      = (const float*)d_in[13];
  const float* pWr     = (const float*)d_in[14];
  const float* pWi     = (const float*)d_in[15];
  const float* pbr     = (const float*)d_in[16];
  const float* pbi     = (const float*)d_in[17];
  const float* convr_k = (const float*)d_in[18];
  const float* convr_b = (const float*)d_in[19];
  const float* convi_k = (const float*)d_in[20];
  const float* convi_b = (const float*)d_in[21];
  const float* fuse_k  = (const float*)d_in[22];
  const float* fuse_b  = (const float*)d_in[23];
  const float* ln_g    = (const float*)d_in[24];
  const float* ln_b    = (const float*)d_in[25];
  float* out = (float*)d_out;

  char* ws = (char*)d_ws;
  float* lamr    = (float*)ws;
  float* lami    = lamr + 2048;
  float* gam     = lami + 2048;
  float* biaseff = gam + 2048;        // 64
  float* ctx     = biaseff + 64;      // 2048
  float* forcing = ctx + 2048;        // 131072
  float* ubuf    = forcing + 131072;  // 131072
  float* hbuf    = ubuf + 131072;     // 131072
  u16* keff_bf   = (u16*)(hbuf + 131072);       // 73728 u16 (144 KB)
  u16* aproj     = keff_bf + 73728;             // 16384 u16 (32 KB)
  size_t off = ((size_t)((char*)(aproj + 16384) - ws) + 255) & ~(size_t)255;
  u32* y_cm32    = (u32*)(ws + off);            // 32 MB (half-batch)
  u16* fused     = (u16*)y_cm32;                // ALIAS: live only after y_cm32 dead
  u16* ynhwc     = (u16*)(ws + off + (size_t)32 * 1024 * 1024);  // 64 MB
  // total ws ~ 97.8 MB

  k_prep<<<8, 256, 0, stream>>>(nu_log, th_log, dnu, dth, lamr, lami, gam);
  k_keff<<<289, 256, 0, stream>>>(fuse_k, fuse_b, convr_k, convr_b, convi_k, convi_b,
                                  keff_bf, biaseff);
  k_apack<<<64, 256, 0, stream>>>(pWr, pWi, aproj);
  k_enc<<<BL * C, 256, 0, stream>>>(x, Vr, Vi, Ur, Ui, ctx, ubuf);
  k_mlp<<<BL, 256, 0, stream>>>(ctx, w1, b1, w2, b2, fscale, forcing);
  k_scan<<<16, 256, 0, stream>>>(lamr, lami, gam, forcing, ubuf, hbuf);
  k_decode<<<1024, 256, 0, stream>>>(hbuf, Ur, Ui, Vr, Vi, y_cm32, 0);
  k_proj<<<256, 256, 0, stream>>>(y_cm32, aproj, pbr, pbi, ynhwc, 0);
  k_decode<<<1024, 256, 0, stream>>>(hbuf, Ur, Ui, Vr, Vi, y_cm32, 16);
  k_proj<<<256, 256, 0, stream>>>(y_cm32, aproj, pbr, pbi, ynhwc, 16);
  k_conv<<<4096, 256, 0, stream>>>(ynhwc, keff_bf, biaseff, fused);
  k_ln<<<BL * C, 256, 0, stream>>>(fused, ln_g, ln_b, x, out);
}